// Round 9
// baseline (132.229 us; speedup 1.0000x reference)
//
#include <hip/hip_runtime.h>

#define SUBS  64
#define WU    208              // IIR warmup steps (>= 200-tap history)
#define RW    48               // output rows per wave (WU+RW = 256 = 32 chunks of 8)
#define RB    (RW * 4)         // rows per block (4 waves)

typedef _Float16 f16x8 __attribute__((ext_vector_type(8)));
typedef float    f32x4 __attribute__((ext_vector_type(4)));

__device__ inline f16x8 ld_frag(const float* p) {
    float4 a = *(const float4*)p;
    float4 b = *(const float4*)(p + 4);
    f16x8 f;
    f[0]=(_Float16)a.x; f[1]=(_Float16)a.y; f[2]=(_Float16)a.z; f[3]=(_Float16)a.w;
    f[4]=(_Float16)b.x; f[5]=(_Float16)b.y; f[6]=(_Float16)b.z; f[7]=(_Float16)b.w;
    return f;
}

// ---------------------------------------------------------------------------
// Kernel 1 (f16 MFMA): Zc = Z @ C^T, base = S + theta + Y @ C^T  (f16 out)
// (unchanged from R7 — proven ~26 us, near its 102 MB memory floor)
// ---------------------------------------------------------------------------
__global__ __launch_bounds__(256, 4) void k_zc_base(
    const float* __restrict__ Z, const float* __restrict__ Y,
    const float* __restrict__ S, const float* __restrict__ C,
    const float* __restrict__ theta,
    _Float16* __restrict__ Zc, _Float16* __restrict__ base, int T)
{
    __shared__ _Float16 bnc[4][16 * 68];      // per-wave bounce tile, stride 68
    const int tid  = threadIdx.x;
    const int lane = tid & 63;
    const int wv   = tid >> 6;
    const int lr   = lane & 15;
    const int lg   = lane >> 4;
    const int tblk = blockIdx.x * 128 + wv * 32;
    _Float16* bw = &bnc[wv][0];

    f16x8 bfr[4][2];
    #pragma unroll
    for (int nt = 0; nt < 4; ++nt)
        #pragma unroll
        for (int ks = 0; ks < 2; ++ks)
            bfr[nt][ks] = ld_frag(&C[(lr + 16 * nt) * 64 + ks * 32 + lg * 8]);

    const float4 th = *(const float4*)&theta[lr * 4];

    #pragma unroll
    for (int g = 0; g < 2; ++g) {
        const int t0 = tblk + g * 16;
        const int rowA = t0 + lr;
        const bool okA = rowA < T;
        f16x8 az[2], ay[2];
        #pragma unroll
        for (int ks = 0; ks < 2; ++ks) {
            if (okA) {
                az[ks] = ld_frag(&Z[(size_t)rowA * 64 + ks * 32 + lg * 8]);
                ay[ks] = ld_frag(&Y[(size_t)rowA * 64 + ks * 32 + lg * 8]);
            } else {
                az[ks] = (f16x8)(_Float16)0.f;
                ay[ks] = (f16x8)(_Float16)0.f;
            }
        }

        f32x4 accZ[4], accY[4];
        #pragma unroll
        for (int nt = 0; nt < 4; ++nt) { accZ[nt] = (f32x4){0,0,0,0}; accY[nt] = (f32x4){0,0,0,0}; }
        #pragma unroll
        for (int nt = 0; nt < 4; ++nt) {
            #pragma unroll
            for (int ks = 0; ks < 2; ++ks) {
                accZ[nt] = __builtin_amdgcn_mfma_f32_16x16x32_f16(az[ks], bfr[nt][ks], accZ[nt], 0, 0, 0);
                accY[nt] = __builtin_amdgcn_mfma_f32_16x16x32_f16(ay[ks], bfr[nt][ks], accY[nt], 0, 0, 0);
            }
        }

        #pragma unroll
        for (int nt = 0; nt < 4; ++nt)
            #pragma unroll
            for (int r = 0; r < 4; ++r)
                bw[(lg * 4 + r) * 68 + lr + 16 * nt] = (_Float16)accZ[nt][r];
        __builtin_amdgcn_wave_barrier();
        #pragma unroll
        for (int i = 0; i < 4; ++i) {
            const int row = i * 4 + lg;
            const int t = t0 + row;
            if (t < T)
                *(ushort4*)&Zc[(size_t)t * 64 + lr * 4] =
                    *(const ushort4*)&bw[row * 68 + lr * 4];
        }
        __builtin_amdgcn_wave_barrier();

        #pragma unroll
        for (int nt = 0; nt < 4; ++nt)
            #pragma unroll
            for (int r = 0; r < 4; ++r)
                bw[(lg * 4 + r) * 68 + lr + 16 * nt] = (_Float16)accY[nt][r];
        __builtin_amdgcn_wave_barrier();
        #pragma unroll
        for (int i = 0; i < 4; ++i) {
            const int row = i * 4 + lg;
            const int t = t0 + row;
            if (t < T) {
                const float4 sv = *(const float4*)&S[(size_t)t * 64 + lr * 4];
                union { _Float16 h[4]; ushort4 u; } pb;
                const _Float16* yb = &bw[row * 68 + lr * 4];
                pb.h[0] = (_Float16)((float)yb[0] + sv.x + th.x);
                pb.h[1] = (_Float16)((float)yb[1] + sv.y + th.y);
                pb.h[2] = (_Float16)((float)yb[2] + sv.z + th.z);
                pb.h[3] = (_Float16)((float)yb[3] + sv.w + th.w);
                *(ushort4*)&base[(size_t)t * 64 + lr * 4] = pb.u;
            }
        }
        __builtin_amdgcn_wave_barrier();
    }
}

// ---------------------------------------------------------------------------
// Kernel 2 (IIR): kern[s][j] = sum_b (K_sb/tau_b) * (j-dl) * r_b^(j-dl),
// r_b = exp(-1/tau_b) -> per basis:  z[m] = 2r z[m-1] - r^2 z[m-2]
//                                          + (c r) x[m-1-dl],  c = K/tau
// filtered[t] = sum_b z_b[t-1];  out = sigmoid(base + filtered)*W + Vo.
// Each wave: 64 channels (lane = s), rows [t0, t0+RW); runs from rest with
// WU=208 warmup steps (truncation tail beyond 200 taps: <= ~2e-3 post-
// sigmoid, threshold 1.38). No LDS; x reads coalesced 128 B/wave.
// ---------------------------------------------------------------------------
__global__ __launch_bounds__(256) void k_iir(
    const _Float16* __restrict__ Zc, const _Float16* __restrict__ base,
    const float* __restrict__ K_spike, const float* __restrict__ tau_spike,
    const float* __restrict__ delta_spike, const float* __restrict__ W,
    const float* __restrict__ Vo, float* __restrict__ out, int T)
{
    const int tid = threadIdx.x;
    const int s   = tid & 63;
    const int wv  = tid >> 6;
    const int t0  = blockIdx.x * RB + wv * RW;
    if (t0 >= T) return;                      // wave-uniform exit, no LDS/sync

    float twr[3], mr2[3], cr[3];
    #pragma unroll
    for (int b = 0; b < 3; ++b) {
        const float tau = __expf(tau_spike[b]);
        const float r   = __expf(-1.0f / tau);
        twr[b] = 2.0f * r;
        mr2[b] = -r * r;
        cr[b]  = K_spike[s * 3 + b] / tau * r;
    }
    const int dl = (int)rintf(delta_spike[s]);
    const int ms = t0 - WU - 1;               // step k: m = ms + k, t = m + 1

    float y1[3] = {0.f, 0.f, 0.f}, y2[3] = {0.f, 0.f, 0.f};

    // ---- warmup: k = 0 .. WU-1 (26 chunks of 8)
    #pragma unroll 1
    for (int ch = 0; ch < WU / 8; ++ch) {
        float xd[8];
        #pragma unroll
        for (int j = 0; j < 8; ++j) {
            const int bi = ms + ch * 8 + j - 1 - dl;
            xd[j] = ((uint)bi < (uint)T) ? (float)Zc[(size_t)bi * 64 + s] : 0.f;
        }
        __builtin_amdgcn_sched_barrier(0);
        #pragma unroll
        for (int j = 0; j < 8; ++j) {
            const float u = xd[j];
            #pragma unroll
            for (int b = 0; b < 3; ++b) {
                const float yn = fmaf(twr[b], y1[b], fmaf(mr2[b], y2[b], cr[b] * u));
                y2[b] = y1[b]; y1[b] = yn;
            }
        }
    }

    // ---- output: k = WU .. WU+RW-1 (6 chunks of 8)
    const float wsub = W[s];
    const float vo   = Vo[0];
    #pragma unroll 1
    for (int ch = 0; ch < RW / 8; ++ch) {
        float xd[8], bb[8];
        #pragma unroll
        for (int j = 0; j < 8; ++j) {
            const int k  = WU + ch * 8 + j;
            const int bi = ms + k - 1 - dl;
            xd[j] = ((uint)bi < (uint)T) ? (float)Zc[(size_t)bi * 64 + s] : 0.f;
            const int t = t0 + ch * 8 + j;
            bb[j] = (t < T) ? (float)base[(size_t)t * 64 + s] : 0.f;
        }
        __builtin_amdgcn_sched_barrier(0);
        #pragma unroll
        for (int j = 0; j < 8; ++j) {
            const float u = xd[j];
            #pragma unroll
            for (int b = 0; b < 3; ++b) {
                const float yn = fmaf(twr[b], y1[b], fmaf(mr2[b], y2[b], cr[b] * u));
                y2[b] = y1[b]; y1[b] = yn;
            }
            const int t = t0 + ch * 8 + j;
            if (t < T) {
                const float xin = bb[j] + y1[0] + y1[1] + y1[2];
                const float sig = 1.0f / (1.0f + __expf(-xin));
                out[(size_t)t * 64 + s] = fmaf(sig, wsub, vo);
            }
        }
    }
}

// ---------------------------------------------------------------------------
extern "C" void kernel_launch(void* const* d_in, const int* in_sizes, int n_in,
                              void* d_out, int out_size, void* d_ws, size_t ws_size,
                              hipStream_t stream)
{
    const float* S     = (const float*)d_in[0];
    const float* Y     = (const float*)d_in[1];
    const float* Z     = (const float*)d_in[2];
    const float* C     = (const float*)d_in[3];
    const float* Vo    = (const float*)d_in[4];
    const float* W     = (const float*)d_in[5];
    const float* theta = (const float*)d_in[6];
    const float* K     = (const float*)d_in[7];
    const float* tau   = (const float*)d_in[8];
    const float* delta = (const float*)d_in[9];
    const int T = in_sizes[0] / SUBS;

    _Float16* Zc   = (_Float16*)d_ws;                               // T*64*2 B
    _Float16* base = (_Float16*)((char*)d_ws + (size_t)T * SUBS * 2);

    k_zc_base<<<(T + 127) / 128, 256, 0, stream>>>(Z, Y, S, C, theta, Zc, base, T);
    k_iir<<<(T + RB - 1) / RB, 256, 0, stream>>>(Zc, base, K, tau, delta, W, Vo,
                                                 (float*)d_out, T);
}

// Round 10
// 63.104 us; speedup vs baseline: 2.0954x; 2.0954x over previous
//
#include <hip/hip_runtime.h>

#define SUBS  64
#define GUARD 256              // zeroed left guard per s-row of Zt
#define NCH   32               // chunks of 8 IIR steps per wave
#define OCH   28               // first output chunk (warmup = 224 steps >= 200 taps)
#define RW    32               // output rows per wave
#define RB    (RW * 4)         // rows per block (4 waves)

typedef _Float16 f16x8 __attribute__((ext_vector_type(8)));
typedef float    f32x4 __attribute__((ext_vector_type(4)));

__device__ inline f16x8 ld_frag(const float* p) {
    float4 a = *(const float4*)p;
    float4 b = *(const float4*)(p + 4);
    f16x8 f;
    f[0]=(_Float16)a.x; f[1]=(_Float16)a.y; f[2]=(_Float16)a.z; f[3]=(_Float16)a.w;
    f[4]=(_Float16)b.x; f[5]=(_Float16)b.y; f[6]=(_Float16)b.z; f[7]=(_Float16)b.w;
    return f;
}
__device__ inline uint pkh2(float a, float b) {
    union { _Float16 h[2]; uint u; } p;
    p.h[0] = (_Float16)a; p.h[1] = (_Float16)b; return p.u;
}

// ---------------------------------------------------------------------------
// Guard zeroing: Zt[s][0..GUARD) = 0 for each s (so k_iir needs no
// conditional loads at t<0; re-run every launch for determinism).
// ---------------------------------------------------------------------------
__global__ __launch_bounds__(256) void k_zguard(_Float16* __restrict__ Zt, int TS)
{
    const int i = blockIdx.x * 256 + threadIdx.x;     // 4096 threads
    const int s = i >> 6;
    const int c = (i & 63) * 4;
    *(ushort4*)&Zt[(size_t)s * TS + c] = make_ushort4(0, 0, 0, 0);
}

// ---------------------------------------------------------------------------
// Kernel 1 (f16 MFMA): Zt[s][t] = (Z @ C^T)[t][s]  (TRANSPOSED, direct from
// D-fragments: lane holds 4 consecutive t of one s -> one 8B store),
// base[t][s] = S + theta + Y @ C^T  (f16, via LDS bounce, coalesced).
// ---------------------------------------------------------------------------
__global__ __launch_bounds__(256, 4) void k_zc_base(
    const float* __restrict__ Z, const float* __restrict__ Y,
    const float* __restrict__ S, const float* __restrict__ C,
    const float* __restrict__ theta,
    _Float16* __restrict__ Zt, _Float16* __restrict__ base, int T, int TS)
{
    __shared__ _Float16 bnc[4][16 * 68];      // per-wave bounce tile, stride 68
    const int tid  = threadIdx.x;
    const int lane = tid & 63;
    const int wv   = tid >> 6;
    const int lr   = lane & 15;
    const int lg   = lane >> 4;
    const int tblk = blockIdx.x * 128 + wv * 32;
    _Float16* bw = &bnc[wv][0];

    f16x8 bfr[4][2];
    #pragma unroll
    for (int nt = 0; nt < 4; ++nt)
        #pragma unroll
        for (int ks = 0; ks < 2; ++ks)
            bfr[nt][ks] = ld_frag(&C[(lr + 16 * nt) * 64 + ks * 32 + lg * 8]);

    const float4 th = *(const float4*)&theta[lr * 4];

    #pragma unroll
    for (int g = 0; g < 2; ++g) {
        const int t0 = tblk + g * 16;
        const int rowA = t0 + lr;
        const bool okA = rowA < T;
        f16x8 az[2], ay[2];
        #pragma unroll
        for (int ks = 0; ks < 2; ++ks) {
            if (okA) {
                az[ks] = ld_frag(&Z[(size_t)rowA * 64 + ks * 32 + lg * 8]);
                ay[ks] = ld_frag(&Y[(size_t)rowA * 64 + ks * 32 + lg * 8]);
            } else {
                az[ks] = (f16x8)(_Float16)0.f;
                ay[ks] = (f16x8)(_Float16)0.f;
            }
        }

        f32x4 accZ[4], accY[4];
        #pragma unroll
        for (int nt = 0; nt < 4; ++nt) { accZ[nt] = (f32x4){0,0,0,0}; accY[nt] = (f32x4){0,0,0,0}; }
        #pragma unroll
        for (int nt = 0; nt < 4; ++nt) {
            #pragma unroll
            for (int ks = 0; ks < 2; ++ks) {
                accZ[nt] = __builtin_amdgcn_mfma_f32_16x16x32_f16(az[ks], bfr[nt][ks], accZ[nt], 0, 0, 0);
                accY[nt] = __builtin_amdgcn_mfma_f32_16x16x32_f16(ay[ks], bfr[nt][ks], accY[nt], 0, 0, 0);
            }
        }

        // ---- Zt (transposed) direct stores: rows t0+lg*4..+3 of column sc
        #pragma unroll
        for (int nt = 0; nt < 4; ++nt) {
            const int sc = lr + 16 * nt;
            const int tt = t0 + lg * 4;
            if (tt + 3 < T) {
                uint2 pk;
                pk.x = pkh2(accZ[nt][0], accZ[nt][1]);
                pk.y = pkh2(accZ[nt][2], accZ[nt][3]);
                *(uint2*)&Zt[(size_t)sc * TS + GUARD + tt] = pk;
            } else {
                #pragma unroll
                for (int r = 0; r < 4; ++r)
                    if (tt + r < T)
                        Zt[(size_t)sc * TS + GUARD + tt + r] = (_Float16)accZ[nt][r];
            }
        }

        // ---- base via bounce (coalesced ushort4)
        #pragma unroll
        for (int nt = 0; nt < 4; ++nt)
            #pragma unroll
            for (int r = 0; r < 4; ++r)
                bw[(lg * 4 + r) * 68 + lr + 16 * nt] = (_Float16)accY[nt][r];
        __builtin_amdgcn_wave_barrier();
        #pragma unroll
        for (int i = 0; i < 4; ++i) {
            const int row = i * 4 + lg;
            const int t = t0 + row;
            if (t < T) {
                const float4 sv = *(const float4*)&S[(size_t)t * 64 + lr * 4];
                union { _Float16 h[4]; ushort4 u; } pb;
                const _Float16* yb = &bw[row * 68 + lr * 4];
                pb.h[0] = (_Float16)((float)yb[0] + sv.x + th.x);
                pb.h[1] = (_Float16)((float)yb[1] + sv.y + th.y);
                pb.h[2] = (_Float16)((float)yb[2] + sv.z + th.z);
                pb.h[3] = (_Float16)((float)yb[3] + sv.w + th.w);
                *(ushort4*)&base[(size_t)t * 64 + lr * 4] = pb.u;
            }
        }
        __builtin_amdgcn_wave_barrier();
    }
}

// ---------------------------------------------------------------------------
// Kernel 2 (IIR, contiguous per-lane feed): per basis b,
//   z[m] = 2r z[m-1] - r^2 z[m-2] + (c r) x[m-1-dl],  r = exp(-1/tau),
//   c = K/tau;  filtered[t] = sum_b z_b[t-1];  out = sigmoid(base+filt)*W+Vo.
// Step k (0..255) consumes x[xi0+k], xi0 = t0-226-dl; outputs at k>=224.
// x loads: 1 dwordx4 per 8 steps from Zt row (per-lane contiguous), depth-4
// static register ring prefetch; per-lane parity via alignbit+cndmask.
// ---------------------------------------------------------------------------
#define SEL4(cur, nxt0, sel)                                                     \
    sel[0] = off ? __builtin_amdgcn_alignbit((cur).y, (cur).x, 16) : (cur).x;    \
    sel[1] = off ? __builtin_amdgcn_alignbit((cur).z, (cur).y, 16) : (cur).y;    \
    sel[2] = off ? __builtin_amdgcn_alignbit((cur).w, (cur).z, 16) : (cur).z;    \
    sel[3] = off ? __builtin_amdgcn_alignbit((nxt0),  (cur).w, 16) : (cur).w;

#define STEP3(u)                                                                 \
    _Pragma("unroll")                                                            \
    for (int b = 0; b < 3; ++b) {                                                \
        const float yn = fmaf(twr[b], y1[b], fmaf(mr2[b], y2[b], cr[b] * (u)));  \
        y2[b] = y1[b]; y1[b] = yn;                                               \
    }

__global__ __launch_bounds__(256, 2) void k_iir(
    const _Float16* __restrict__ Zt, const _Float16* __restrict__ base,
    const float* __restrict__ K_spike, const float* __restrict__ tau_spike,
    const float* __restrict__ delta_spike, const float* __restrict__ W,
    const float* __restrict__ Vo, float* __restrict__ out, int T, int TS)
{
    const int tid = threadIdx.x;
    const int s   = tid & 63;
    const int wv  = tid >> 6;
    const int t0  = blockIdx.x * RB + wv * RW;
    if (t0 >= T) return;

    float twr[3], mr2[3], cr[3];
    #pragma unroll
    for (int b = 0; b < 3; ++b) {
        const float tau = __expf(tau_spike[b]);
        const float r   = __expf(-1.0f / tau);
        twr[b] = 2.0f * r;
        mr2[b] = -r * r;
        cr[b]  = K_spike[s * 3 + b] / tau * r;
    }
    int dl = (int)rintf(delta_spike[s]);
    dl = min(max(dl, 0), 30);                 // guard covers 226+30 <= GUARD+0

    const int xi0 = t0 - 8 * NCH + RW - 2 - dl;   // t0 - 226 - dl
    const int xb0 = xi0 & ~1;
    const uint off = (uint)(xi0 & 1);

    const _Float16* rowp = Zt + (size_t)s * TS + GUARD;
    const uint4* xp = (const uint4*)(rowp + xb0);

    // preload base for this wave's 32 output rows (hides under warmup)
    _Float16 bb[RW];
    #pragma unroll
    for (int o = 0; o < RW; ++o) {
        const int tt = min(t0 + o, T - 1);
        bb[o] = base[(size_t)tt * 64 + s];
    }

    uint4 buf[4];
    #pragma unroll
    for (int p = 0; p < 4; ++p) buf[p] = xp[p];

    float y1[3] = {0.f, 0.f, 0.f}, y2[3] = {0.f, 0.f, 0.f};

    // ---- warmup chunks 0..27 (each prefetches chunk c+4; ring static by unroll 4)
    #pragma unroll 4
    for (int c = 0; c < OCH; ++c) {
        const uint4 cur  = buf[c & 3];
        const uint  nxt0 = buf[(c + 1) & 3].x;
        buf[c & 3] = xp[c + 4];               // c+4 <= 31
        __builtin_amdgcn_sched_barrier(0);
        uint sel[4];
        SEL4(cur, nxt0, sel);
        #pragma unroll
        for (int i = 0; i < 4; ++i) {
            union { uint u; _Float16 h[2]; } w; w.u = sel[i];
            STEP3((float)w.h[0]);
            STEP3((float)w.h[1]);
        }
    }

    // ---- output chunks 28..31 (fully unrolled -> static bb/o indices)
    const float wsub = W[s];
    const float vo   = Vo[0];
    #pragma unroll
    for (int c = OCH; c < NCH; ++c) {
        const uint4 cur  = buf[c & 3];
        const uint  nxt0 = (c < NCH - 1) ? buf[(c + 1) & 3].x : 0u;
        uint sel[4];
        SEL4(cur, nxt0, sel);
        #pragma unroll
        for (int i = 0; i < 4; ++i) {
            union { uint u; _Float16 h[2]; } w; w.u = sel[i];
            #pragma unroll
            for (int hh = 0; hh < 2; ++hh) {
                STEP3((float)w.h[hh]);
                const int o = (c - OCH) * 8 + i * 2 + hh;
                const int t = t0 + o;
                if (t < T) {
                    const float xin = (float)bb[o] + y1[0] + y1[1] + y1[2];
                    const float sig = 1.0f / (1.0f + __expf(-xin));
                    out[(size_t)t * 64 + s] = fmaf(sig, wsub, vo);
                }
            }
        }
    }
}

// ---------------------------------------------------------------------------
extern "C" void kernel_launch(void* const* d_in, const int* in_sizes, int n_in,
                              void* d_out, int out_size, void* d_ws, size_t ws_size,
                              hipStream_t stream)
{
    const float* S     = (const float*)d_in[0];
    const float* Y     = (const float*)d_in[1];
    const float* Z     = (const float*)d_in[2];
    const float* C     = (const float*)d_in[3];
    const float* Vo    = (const float*)d_in[4];
    const float* W     = (const float*)d_in[5];
    const float* theta = (const float*)d_in[6];
    const float* K     = (const float*)d_in[7];
    const float* tau   = (const float*)d_in[8];
    const float* delta = (const float*)d_in[9];
    const int T  = in_sizes[0] / SUBS;
    const int TS = T + GUARD;

    _Float16* Zt   = (_Float16*)d_ws;                               // 64*TS*2 B
    _Float16* base = (_Float16*)((char*)d_ws + (size_t)SUBS * TS * 2);

    k_zguard<<<16, 256, 0, stream>>>(Zt, TS);
    k_zc_base<<<(T + 127) / 128, 256, 0, stream>>>(Z, Y, S, C, theta, Zt, base, T, TS);
    k_iir<<<(T + RB - 1) / RB, 256, 0, stream>>>(Zt, base, K, tau, delta, W, Vo,
                                                 (float*)d_out, T, TS);
}

// Round 11
// 60.834 us; speedup vs baseline: 2.1736x; 1.0373x over previous
//
#include <hip/hip_runtime.h>

#define SUBS  64
#define GUARD 256              // zeroed left guard per s-row of Zt
#define NCH   32               // chunks of 8 IIR steps per wave
#define OCH   28               // first output chunk (warmup = 224 steps >= 200 taps)
#define RW    32               // output rows per wave
#define RB    (RW * 4)         // rows per block (4 waves)

typedef _Float16 f16x8 __attribute__((ext_vector_type(8)));
typedef float    f32x4 __attribute__((ext_vector_type(4)));

__device__ inline f16x8 ld_frag(const float* p) {
    float4 a = *(const float4*)p;
    float4 b = *(const float4*)(p + 4);
    f16x8 f;
    f[0]=(_Float16)a.x; f[1]=(_Float16)a.y; f[2]=(_Float16)a.z; f[3]=(_Float16)a.w;
    f[4]=(_Float16)b.x; f[5]=(_Float16)b.y; f[6]=(_Float16)b.z; f[7]=(_Float16)b.w;
    return f;
}
__device__ inline uint pkh2(float a, float b) {
    union { _Float16 h[2]; uint u; } p;
    p.h[0] = (_Float16)a; p.h[1] = (_Float16)b; return p.u;
}

// ---------------------------------------------------------------------------
// Guard zeroing: Zt[s][0..GUARD) = 0.
// ---------------------------------------------------------------------------
__global__ __launch_bounds__(256) void k_zguard(_Float16* __restrict__ Zt, int TS)
{
    const int i = blockIdx.x * 256 + threadIdx.x;     // 4096 threads
    const int s = i >> 6;
    const int c = (i & 63) * 4;
    *(ushort4*)&Zt[(size_t)s * TS + c] = make_ushort4(0, 0, 0, 0);
}

// ---------------------------------------------------------------------------
// Kernel 1 (f16 MFMA): Zt[s][t] = (Z @ C^T)[t][s] (transposed), coalesced via
// block LDS tile [64][136] + cooperative [64][128] store (16 lanes per 256B
// s-row). base[t][s] = S + theta + Y @ C^T via per-wave bounce (unchanged).
// ---------------------------------------------------------------------------
__global__ __launch_bounds__(256, 4) void k_zc_base(
    const float* __restrict__ Z, const float* __restrict__ Y,
    const float* __restrict__ S, const float* __restrict__ C,
    const float* __restrict__ theta,
    _Float16* __restrict__ Zt, _Float16* __restrict__ base, int T, int TS)
{
    __shared__ _Float16 ztl[SUBS * 136];      // 17408 B, row stride 136 halves
    __shared__ _Float16 bnc[4][16 * 68];      // 8704 B per-wave bounce
    const int tid  = threadIdx.x;
    const int lane = tid & 63;
    const int wv   = tid >> 6;
    const int lr   = lane & 15;
    const int lg   = lane >> 4;
    const int t0b  = blockIdx.x * 128;
    const int tblk = t0b + wv * 32;
    _Float16* bw = &bnc[wv][0];

    f16x8 bfr[4][2];
    #pragma unroll
    for (int nt = 0; nt < 4; ++nt)
        #pragma unroll
        for (int ks = 0; ks < 2; ++ks)
            bfr[nt][ks] = ld_frag(&C[(lr + 16 * nt) * 64 + ks * 32 + lg * 8]);

    const float4 th = *(const float4*)&theta[lr * 4];

    #pragma unroll
    for (int g = 0; g < 2; ++g) {
        const int t0 = tblk + g * 16;
        const int rowA = t0 + lr;
        const bool okA = rowA < T;
        f16x8 az[2], ay[2];
        #pragma unroll
        for (int ks = 0; ks < 2; ++ks) {
            if (okA) {
                az[ks] = ld_frag(&Z[(size_t)rowA * 64 + ks * 32 + lg * 8]);
                ay[ks] = ld_frag(&Y[(size_t)rowA * 64 + ks * 32 + lg * 8]);
            } else {
                az[ks] = (f16x8)(_Float16)0.f;
                ay[ks] = (f16x8)(_Float16)0.f;
            }
        }

        f32x4 accZ[4], accY[4];
        #pragma unroll
        for (int nt = 0; nt < 4; ++nt) { accZ[nt] = (f32x4){0,0,0,0}; accY[nt] = (f32x4){0,0,0,0}; }
        #pragma unroll
        for (int nt = 0; nt < 4; ++nt) {
            #pragma unroll
            for (int ks = 0; ks < 2; ++ks) {
                accZ[nt] = __builtin_amdgcn_mfma_f32_16x16x32_f16(az[ks], bfr[nt][ks], accZ[nt], 0, 0, 0);
                accY[nt] = __builtin_amdgcn_mfma_f32_16x16x32_f16(ay[ks], bfr[nt][ks], accY[nt], 0, 0, 0);
            }
        }

        // ---- Zt into block LDS tile: lane holds 4 consecutive t of s=sc
        #pragma unroll
        for (int nt = 0; nt < 4; ++nt) {
            const int sc = lr + 16 * nt;
            const int lt = wv * 32 + g * 16 + lg * 4;
            uint2 pk;
            pk.x = pkh2(accZ[nt][0], accZ[nt][1]);
            pk.y = pkh2(accZ[nt][2], accZ[nt][3]);
            *(uint2*)&ztl[sc * 136 + lt] = pk;
        }

        // ---- base via bounce (coalesced ushort4)
        #pragma unroll
        for (int nt = 0; nt < 4; ++nt)
            #pragma unroll
            for (int r = 0; r < 4; ++r)
                bw[(lg * 4 + r) * 68 + lr + 16 * nt] = (_Float16)accY[nt][r];
        __builtin_amdgcn_wave_barrier();
        #pragma unroll
        for (int i = 0; i < 4; ++i) {
            const int row = i * 4 + lg;
            const int t = t0 + row;
            if (t < T) {
                const float4 sv = *(const float4*)&S[(size_t)t * 64 + lr * 4];
                union { _Float16 h[4]; ushort4 u; } pb;
                const _Float16* yb = &bw[row * 68 + lr * 4];
                pb.h[0] = (_Float16)((float)yb[0] + sv.x + th.x);
                pb.h[1] = (_Float16)((float)yb[1] + sv.y + th.y);
                pb.h[2] = (_Float16)((float)yb[2] + sv.z + th.z);
                pb.h[3] = (_Float16)((float)yb[3] + sv.w + th.w);
                *(ushort4*)&base[(size_t)t * 64 + lr * 4] = pb.u;
            }
        }
        __builtin_amdgcn_wave_barrier();
    }

    __syncthreads();

    // ---- cooperative coalesced Zt store: 1024 chunks of 8 halves (16B)
    #pragma unroll
    for (int it = 0; it < 4; ++it) {
        const int chunk = tid + it * 256;
        const int row = chunk >> 4;           // s
        const int col = chunk & 15;           // 8-half group within 128 t
        const int tb  = t0b + col * 8;
        const uint4 v = *(const uint4*)&ztl[row * 136 + col * 8];
        if (tb + 7 < T) {
            *(uint4*)&Zt[(size_t)row * TS + GUARD + tb] = v;
        } else {
            #pragma unroll
            for (int h = 0; h < 8; ++h)
                if (tb + h < T)
                    Zt[(size_t)row * TS + GUARD + tb + h] = ztl[row * 136 + col * 8 + h];
        }
    }
}

// ---------------------------------------------------------------------------
// Kernel 2 (IIR, contiguous per-lane feed, depth-8 prefetch ring):
//   z[m] = 2r z[m-1] - r^2 z[m-2] + (c r) x[m-1-dl];  filtered[t] = sum_b z_b
//   out = sigmoid(base + filtered) * W + Vo.
// ---------------------------------------------------------------------------
#define SEL4(cur, nxt0, sel)                                                     \
    sel[0] = off ? __builtin_amdgcn_alignbit((cur).y, (cur).x, 16) : (cur).x;    \
    sel[1] = off ? __builtin_amdgcn_alignbit((cur).z, (cur).y, 16) : (cur).y;    \
    sel[2] = off ? __builtin_amdgcn_alignbit((cur).w, (cur).z, 16) : (cur).z;    \
    sel[3] = off ? __builtin_amdgcn_alignbit((nxt0),  (cur).w, 16) : (cur).w;

#define STEP3(u)                                                                 \
    _Pragma("unroll")                                                            \
    for (int b = 0; b < 3; ++b) {                                                \
        const float yn = fmaf(twr[b], y1[b], fmaf(mr2[b], y2[b], cr[b] * (u)));  \
        y2[b] = y1[b]; y1[b] = yn;                                               \
    }

#define CHUNK8(cur, nxt0)                                                        \
    {                                                                            \
        uint sel[4];                                                             \
        SEL4(cur, nxt0, sel);                                                    \
        _Pragma("unroll")                                                        \
        for (int i = 0; i < 4; ++i) {                                            \
            union { uint u; _Float16 h[2]; } w; w.u = sel[i];                    \
            STEP3((float)w.h[0]);                                                \
            STEP3((float)w.h[1]);                                                \
        }                                                                        \
    }

__global__ __launch_bounds__(256, 3) void k_iir(
    const _Float16* __restrict__ Zt, const _Float16* __restrict__ base,
    const float* __restrict__ K_spike, const float* __restrict__ tau_spike,
    const float* __restrict__ delta_spike, const float* __restrict__ W,
    const float* __restrict__ Vo, float* __restrict__ out, int T, int TS)
{
    const int tid = threadIdx.x;
    const int s   = tid & 63;
    const int wv  = tid >> 6;
    const int t0  = blockIdx.x * RB + wv * RW;
    if (t0 >= T) return;

    float twr[3], mr2[3], cr[3];
    #pragma unroll
    for (int b = 0; b < 3; ++b) {
        const float tau = __expf(tau_spike[b]);
        const float r   = __expf(-1.0f / tau);
        twr[b] = 2.0f * r;
        mr2[b] = -r * r;
        cr[b]  = K_spike[s * 3 + b] / tau * r;
    }
    int dl = (int)rintf(delta_spike[s]);
    dl = min(max(dl, 0), 30);                 // guard covers 226+30 <= GUARD

    const int xi0 = t0 - 8 * NCH + RW - 2 - dl;   // t0 - 226 - dl
    const int xb0 = xi0 & ~1;
    const uint off = (uint)(xi0 & 1);

    const _Float16* rowp = Zt + (size_t)s * TS + GUARD;
    const uint4* xp = (const uint4*)(rowp + xb0);

    // preload base for this wave's 32 output rows (hides under warmup)
    _Float16 bb[RW];
    #pragma unroll
    for (int o = 0; o < RW; ++o) {
        const int tt = min(t0 + o, T - 1);
        bb[o] = base[(size_t)tt * 64 + s];
    }

    uint4 buf[8];
    #pragma unroll
    for (int p = 0; p < 8; ++p) buf[p] = xp[p];

    float y1[3] = {0.f, 0.f, 0.f}, y2[3] = {0.f, 0.f, 0.f};

    // ---- warmup c = 0..23 (depth-8 ring, static indices via inner unroll)
    #pragma unroll 1
    for (int cc = 0; cc < 3; ++cc) {
        #pragma unroll
        for (int j = 0; j < 8; ++j) {
            const int c = cc * 8 + j;
            const uint4 cur  = buf[j];
            const uint  nxt0 = buf[(j + 1) & 7].x;
            buf[j] = xp[c + 8];               // c+8 <= 31
            __builtin_amdgcn_sched_barrier(0);
            CHUNK8(cur, nxt0);
        }
    }
    // ---- warmup c = 24..27 (no prefetch; chunks live in buf[0..3])
    #pragma unroll
    for (int j = 0; j < 4; ++j) {
        const uint4 cur  = buf[j];
        const uint  nxt0 = buf[j + 1].x;
        CHUNK8(cur, nxt0);
    }

    // ---- output c = 28..31 (buf[4..7]), fully unrolled
    const float wsub = W[s];
    const float vo   = Vo[0];
    #pragma unroll
    for (int j = 4; j < 8; ++j) {
        const uint4 cur  = buf[j];
        const uint  nxt0 = (j < 7) ? buf[j + 1].x : 0u;
        uint sel[4];
        SEL4(cur, nxt0, sel);
        #pragma unroll
        for (int i = 0; i < 4; ++i) {
            union { uint u; _Float16 h[2]; } w; w.u = sel[i];
            #pragma unroll
            for (int hh = 0; hh < 2; ++hh) {
                STEP3((float)w.h[hh]);
                const int o = (j - 4) * 8 + i * 2 + hh;
                const int t = t0 + o;
                if (t < T) {
                    const float xin = (float)bb[o] + y1[0] + y1[1] + y1[2];
                    const float sig = 1.0f / (1.0f + __expf(-xin));
                    out[(size_t)t * 64 + s] = fmaf(sig, wsub, vo);
                }
            }
        }
    }
}

// ---------------------------------------------------------------------------
extern "C" void kernel_launch(void* const* d_in, const int* in_sizes, int n_in,
                              void* d_out, int out_size, void* d_ws, size_t ws_size,
                              hipStream_t stream)
{
    const float* S     = (const float*)d_in[0];
    const float* Y     = (const float*)d_in[1];
    const float* Z     = (const float*)d_in[2];
    const float* C     = (const float*)d_in[3];
    const float* Vo    = (const float*)d_in[4];
    const float* W     = (const float*)d_in[5];
    const float* theta = (const float*)d_in[6];
    const float* K     = (const float*)d_in[7];
    const float* tau   = (const float*)d_in[8];
    const float* delta = (const float*)d_in[9];
    const int T  = in_sizes[0] / SUBS;
    const int TS = T + GUARD;

    _Float16* Zt   = (_Float16*)d_ws;                               // 64*TS*2 B
    _Float16* base = (_Float16*)((char*)d_ws + (size_t)SUBS * TS * 2);

    k_zguard<<<16, 256, 0, stream>>>(Zt, TS);
    k_zc_base<<<(T + 127) / 128, 256, 0, stream>>>(Z, Y, S, C, theta, Zt, base, T, TS);
    k_iir<<<(T + RB - 1) / RB, 256, 0, stream>>>(Zt, base, K, tau, delta, W, Vo,
                                                 (float*)d_out, T, TS);
}

// Round 12
// 57.023 us; speedup vs baseline: 2.3189x; 1.0668x over previous
//
#include <hip/hip_runtime.h>

#define SUBS  64
#define GUARD 256              // zeroed left guard per s-row of Zt
#define NCH   32               // chunks of 8 IIR steps per wave
#define OCH   28               // first output chunk (warmup = 224 steps >= 200 taps)
#define RW    32               // output rows per wave
#define RB    (RW * 4)         // rows per block (4 waves)

typedef _Float16 f16x8 __attribute__((ext_vector_type(8)));
typedef float    f32x4 __attribute__((ext_vector_type(4)));

__device__ inline f16x8 ld_frag(const float* p) {
    float4 a = *(const float4*)p;
    float4 b = *(const float4*)(p + 4);
    f16x8 f;
    f[0]=(_Float16)a.x; f[1]=(_Float16)a.y; f[2]=(_Float16)a.z; f[3]=(_Float16)a.w;
    f[4]=(_Float16)b.x; f[5]=(_Float16)b.y; f[6]=(_Float16)b.z; f[7]=(_Float16)b.w;
    return f;
}
__device__ inline uint pkh2(float a, float b) {
    union { _Float16 h[2]; uint u; } p;
    p.h[0] = (_Float16)a; p.h[1] = (_Float16)b; return p.u;
}

// ---------------------------------------------------------------------------
// Kernel 1 (f16 MFMA): Zt[s][t] = (Z @ C^T)[t][s], Yt[s][t] = (Y @ C^T)[t][s]
// — both transposed via block LDS tiles + cooperative coalesced stores.
// Blocks 0..7 additionally zero the GUARD region of Zt (merged k_zguard).
// No S/theta here (moved to k_iir to balance HBM traffic between kernels).
// ---------------------------------------------------------------------------
__global__ __launch_bounds__(256, 4) void k_mm(
    const float* __restrict__ Z, const float* __restrict__ Y,
    const float* __restrict__ C,
    _Float16* __restrict__ Zt, _Float16* __restrict__ Yt, int T, int TS)
{
    __shared__ _Float16 ztl[SUBS * 136];      // 17408 B, row stride 136 halves
    __shared__ _Float16 ytl[SUBS * 136];      // 17408 B
    const int tid  = threadIdx.x;
    const int lane = tid & 63;
    const int wv   = tid >> 6;
    const int lr   = lane & 15;
    const int lg   = lane >> 4;
    const int t0b  = blockIdx.x * 128;

    // merged guard zeroing: 8 blocks x 256 thr x 16B = 64 rows x 256 halves
    if (blockIdx.x < 8) {
        const int chunk = blockIdx.x * 256 + tid;
        const int s = chunk >> 5;
        const int c = (chunk & 31) * 8;
        uint4 z4 = {0, 0, 0, 0};
        *(uint4*)&Zt[(size_t)s * TS + c] = z4;
    }

    f16x8 bfr[4][2];
    #pragma unroll
    for (int nt = 0; nt < 4; ++nt)
        #pragma unroll
        for (int ks = 0; ks < 2; ++ks)
            bfr[nt][ks] = ld_frag(&C[(lr + 16 * nt) * 64 + ks * 32 + lg * 8]);

    #pragma unroll
    for (int g = 0; g < 2; ++g) {
        const int t0 = t0b + wv * 32 + g * 16;
        const int rowA = t0 + lr;
        const bool okA = rowA < T;
        f16x8 az[2], ay[2];
        #pragma unroll
        for (int ks = 0; ks < 2; ++ks) {
            if (okA) {
                az[ks] = ld_frag(&Z[(size_t)rowA * 64 + ks * 32 + lg * 8]);
                ay[ks] = ld_frag(&Y[(size_t)rowA * 64 + ks * 32 + lg * 8]);
            } else {
                az[ks] = (f16x8)(_Float16)0.f;
                ay[ks] = (f16x8)(_Float16)0.f;
            }
        }

        f32x4 accZ[4], accY[4];
        #pragma unroll
        for (int nt = 0; nt < 4; ++nt) { accZ[nt] = (f32x4){0,0,0,0}; accY[nt] = (f32x4){0,0,0,0}; }
        #pragma unroll
        for (int nt = 0; nt < 4; ++nt) {
            #pragma unroll
            for (int ks = 0; ks < 2; ++ks) {
                accZ[nt] = __builtin_amdgcn_mfma_f32_16x16x32_f16(az[ks], bfr[nt][ks], accZ[nt], 0, 0, 0);
                accY[nt] = __builtin_amdgcn_mfma_f32_16x16x32_f16(ay[ks], bfr[nt][ks], accY[nt], 0, 0, 0);
            }
        }

        // lane holds 4 consecutive t of channel sc -> one uint2 per tile
        #pragma unroll
        for (int nt = 0; nt < 4; ++nt) {
            const int sc = lr + 16 * nt;
            const int lt = wv * 32 + g * 16 + lg * 4;
            uint2 pz, py;
            pz.x = pkh2(accZ[nt][0], accZ[nt][1]);
            pz.y = pkh2(accZ[nt][2], accZ[nt][3]);
            py.x = pkh2(accY[nt][0], accY[nt][1]);
            py.y = pkh2(accY[nt][2], accY[nt][3]);
            *(uint2*)&ztl[sc * 136 + lt] = pz;
            *(uint2*)&ytl[sc * 136 + lt] = py;
        }
    }

    __syncthreads();

    // cooperative coalesced stores: per tile 1024 chunks of 8 halves (16B)
    #pragma unroll
    for (int it = 0; it < 4; ++it) {
        const int chunk = tid + it * 256;
        const int row = chunk >> 4;           // s
        const int col = chunk & 15;           // 8-half group within 128 t
        const int tb  = t0b + col * 8;
        const uint4 vz = *(const uint4*)&ztl[row * 136 + col * 8];
        const uint4 vy = *(const uint4*)&ytl[row * 136 + col * 8];
        if (tb + 7 < T) {
            *(uint4*)&Zt[(size_t)row * TS + GUARD + tb] = vz;
            *(uint4*)&Yt[(size_t)row * TS + GUARD + tb] = vy;
        } else {
            #pragma unroll
            for (int h = 0; h < 8; ++h)
                if (tb + h < T) {
                    Zt[(size_t)row * TS + GUARD + tb + h] = ztl[row * 136 + col * 8 + h];
                    Yt[(size_t)row * TS + GUARD + tb + h] = ytl[row * 136 + col * 8 + h];
                }
        }
    }
}

// ---------------------------------------------------------------------------
// Kernel 2 (IIR): z[m] = 2r z[m-1] - r^2 z[m-2] + (c r) x[m-1-dl] per basis;
// filtered[t] = sum_b z_b[t-1]; out = sigmoid(Yc + S + theta + filt)*W + Vo.
// Contiguous per-lane Zt feed, depth-8 prefetch ring; Yc from transposed Yt
// (4x dwordx4/lane); S preloaded f32 (latency hidden under warmup).
// ---------------------------------------------------------------------------
#define SEL4(cur, nxt0, sel)                                                     \
    sel[0] = off ? __builtin_amdgcn_alignbit((cur).y, (cur).x, 16) : (cur).x;    \
    sel[1] = off ? __builtin_amdgcn_alignbit((cur).z, (cur).y, 16) : (cur).y;    \
    sel[2] = off ? __builtin_amdgcn_alignbit((cur).w, (cur).z, 16) : (cur).z;    \
    sel[3] = off ? __builtin_amdgcn_alignbit((nxt0),  (cur).w, 16) : (cur).w;

#define STEP3(u)                                                                 \
    _Pragma("unroll")                                                            \
    for (int b = 0; b < 3; ++b) {                                                \
        const float yn = fmaf(twr[b], y1[b], fmaf(mr2[b], y2[b], cr[b] * (u)));  \
        y2[b] = y1[b]; y1[b] = yn;                                               \
    }

#define CHUNK8(cur, nxt0)                                                        \
    {                                                                            \
        uint sel[4];                                                             \
        SEL4(cur, nxt0, sel);                                                    \
        _Pragma("unroll")                                                        \
        for (int i = 0; i < 4; ++i) {                                            \
            union { uint u; _Float16 h[2]; } w; w.u = sel[i];                    \
            STEP3((float)w.h[0]);                                                \
            STEP3((float)w.h[1]);                                                \
        }                                                                        \
    }

__global__ __launch_bounds__(256, 3) void k_iir(
    const _Float16* __restrict__ Zt, const _Float16* __restrict__ Yt,
    const float* __restrict__ S,
    const float* __restrict__ K_spike, const float* __restrict__ tau_spike,
    const float* __restrict__ delta_spike, const float* __restrict__ theta,
    const float* __restrict__ W, const float* __restrict__ Vo,
    float* __restrict__ out, int T, int TS)
{
    const int tid = threadIdx.x;
    const int s   = tid & 63;
    const int wv  = tid >> 6;
    const int t0  = blockIdx.x * RB + wv * RW;
    if (t0 >= T) return;

    float twr[3], mr2[3], cr[3];
    #pragma unroll
    for (int b = 0; b < 3; ++b) {
        const float tau = __expf(tau_spike[b]);
        const float r   = __expf(-1.0f / tau);
        twr[b] = 2.0f * r;
        mr2[b] = -r * r;
        cr[b]  = K_spike[s * 3 + b] / tau * r;
    }
    int dl = (int)rintf(delta_spike[s]);
    dl = min(max(dl, 0), 30);                 // guard covers 226+30 <= GUARD

    const int xi0 = t0 - 8 * NCH + RW - 2 - dl;   // t0 - 226 - dl
    const int xb0 = xi0 & ~1;
    const uint off = (uint)(xi0 & 1);

    const _Float16* rowp = Zt + (size_t)s * TS + GUARD;
    const uint4* xp = (const uint4*)(rowp + xb0);

    // preload Yc (transposed, contiguous) + S rows (latency hides under warmup)
    uint4 yv[4];
    {
        const uint4* yp = (const uint4*)(Yt + (size_t)s * TS + GUARD + t0);
        #pragma unroll
        for (int p = 0; p < 4; ++p) yv[p] = yp[p];
    }
    float sreg[RW];
    #pragma unroll
    for (int o = 0; o < RW; ++o) {
        const int tt = min(t0 + o, T - 1);
        sreg[o] = S[(size_t)tt * 64 + s];
    }

    uint4 buf[8];
    #pragma unroll
    for (int p = 0; p < 8; ++p) buf[p] = xp[p];

    float y1[3] = {0.f, 0.f, 0.f}, y2[3] = {0.f, 0.f, 0.f};

    // ---- warmup c = 0..23 (depth-8 ring, static indices via inner unroll)
    #pragma unroll 1
    for (int cc = 0; cc < 3; ++cc) {
        #pragma unroll
        for (int j = 0; j < 8; ++j) {
            const int c = cc * 8 + j;
            const uint4 cur  = buf[j];
            const uint  nxt0 = buf[(j + 1) & 7].x;
            buf[j] = xp[c + 8];               // c+8 <= 31
            __builtin_amdgcn_sched_barrier(0);
            CHUNK8(cur, nxt0);
        }
    }
    // ---- warmup c = 24..27 (no prefetch; chunks live in buf[0..3])
    #pragma unroll
    for (int j = 0; j < 4; ++j) {
        const uint4 cur  = buf[j];
        const uint  nxt0 = buf[j + 1].x;
        CHUNK8(cur, nxt0);
    }

    // ---- output c = 28..31 (buf[4..7]), fully unrolled
    const float wsub = W[s];
    const float vo   = Vo[0];
    const float th   = theta[s];
    #pragma unroll
    for (int j = 4; j < 8; ++j) {
        const uint4 cur  = buf[j];
        const uint  nxt0 = (j < 7) ? buf[j + 1].x : 0u;
        uint sel[4];
        SEL4(cur, nxt0, sel);
        union { uint4 v; _Float16 h[8]; } yw;
        yw.v = yv[j - 4];
        #pragma unroll
        for (int i = 0; i < 4; ++i) {
            union { uint u; _Float16 h[2]; } w; w.u = sel[i];
            #pragma unroll
            for (int hh = 0; hh < 2; ++hh) {
                STEP3((float)w.h[hh]);
                const int o = (j - 4) * 8 + i * 2 + hh;
                const int t = t0 + o;
                if (t < T) {
                    const float xin = (float)yw.h[i * 2 + hh] + sreg[o] + th
                                      + y1[0] + y1[1] + y1[2];
                    const float sig = 1.0f / (1.0f + __expf(-xin));
                    out[(size_t)t * 64 + s] = fmaf(sig, wsub, vo);
                }
            }
        }
    }
}

// ---------------------------------------------------------------------------
extern "C" void kernel_launch(void* const* d_in, const int* in_sizes, int n_in,
                              void* d_out, int out_size, void* d_ws, size_t ws_size,
                              hipStream_t stream)
{
    const float* S     = (const float*)d_in[0];
    const float* Y     = (const float*)d_in[1];
    const float* Z     = (const float*)d_in[2];
    const float* C     = (const float*)d_in[3];
    const float* Vo    = (const float*)d_in[4];
    const float* W     = (const float*)d_in[5];
    const float* theta = (const float*)d_in[6];
    const float* K     = (const float*)d_in[7];
    const float* tau   = (const float*)d_in[8];
    const float* delta = (const float*)d_in[9];
    const int T  = in_sizes[0] / SUBS;
    const int TS = T + GUARD;

    _Float16* Zt = (_Float16*)d_ws;                                 // 64*TS*2 B
    _Float16* Yt = (_Float16*)((char*)d_ws + (size_t)SUBS * TS * 2);

    k_mm<<<(T + 127) / 128, 256, 0, stream>>>(Z, Y, C, Zt, Yt, T, TS);
    k_iir<<<(T + RB - 1) / RB, 256, 0, stream>>>(Zt, Yt, S, K, tau, delta, theta,
                                                 W, Vo, (float*)d_out, T, TS);
}

// Round 13
// 56.305 us; speedup vs baseline: 2.3484x; 1.0127x over previous
//
#include <hip/hip_runtime.h>

#define SUBS  64
#define GUARD 256              // left guard halves per channel (32 tiles)
#define NCH   34               // chunks of 8 IIR steps per wave (272 steps)
#define WU    224              // warmup steps (chunks 0..27)
#define RW    48               // output rows per wave (chunks 28..33)
#define RB    (RW * 4)         // rows per block (4 waves)
#define LSTR  136              // k_mm LDS row stride (halves; 272B, 16B-aligned)

typedef _Float16 f16x8 __attribute__((ext_vector_type(8)));
typedef float    f32x4 __attribute__((ext_vector_type(4)));

__device__ inline f16x8 ld_frag(const float* p) {
    float4 a = *(const float4*)p;
    float4 b = *(const float4*)(p + 4);
    f16x8 f;
    f[0]=(_Float16)a.x; f[1]=(_Float16)a.y; f[2]=(_Float16)a.z; f[3]=(_Float16)a.w;
    f[4]=(_Float16)b.x; f[5]=(_Float16)b.y; f[6]=(_Float16)b.z; f[7]=(_Float16)b.w;
    return f;
}
__device__ inline uint pkh2(float a, float b) {
    union { _Float16 h[2]; uint u; } p;
    p.h[0] = (_Float16)a; p.h[1] = (_Float16)b; return p.u;
}

// ---------------------------------------------------------------------------
// Kernel 1 (f16 MFMA): tiled-transposed Zt/Yt: layout [tile][64 s][8 halves],
// tile = 8 consecutive t. Lane-s 16B chunk at tile*1024+s*16 -> k_iir loads
// are wave-coalesced. Blocks 0..7 zero the 32 left-guard tiles, blocks 8..17
// zero 40 right-guard tiles (both arrays; disjoint from data writes).
// ---------------------------------------------------------------------------
__global__ __launch_bounds__(256, 4) void k_mm(
    const float* __restrict__ Z, const float* __restrict__ Y,
    const float* __restrict__ C,
    _Float16* __restrict__ Zt, _Float16* __restrict__ Yt, int T, int rgz)
{
    __shared__ _Float16 ztl[SUBS * LSTR];     // 17408 B
    __shared__ _Float16 ytl[SUBS * LSTR];     // 17408 B
    const int tid  = threadIdx.x;
    const int lane = tid & 63;
    const int wv   = tid >> 6;
    const int lr   = lane & 15;
    const int lg   = lane >> 4;
    const int t0b  = blockIdx.x * 128;

    // merged guard zeroing (16B per thread per array)
    if (blockIdx.x < 8) {                     // left guard: tiles 0..31
        const int tile = blockIdx.x * 4 + (tid >> 6);
        uint4 z4 = {0, 0, 0, 0};
        ((uint4*)Zt)[(size_t)tile * 64 + (tid & 63)] = z4;
        ((uint4*)Yt)[(size_t)tile * 64 + (tid & 63)] = z4;
    } else if (blockIdx.x < 18) {             // right guard: tiles rgz..rgz+39
        const int tile = rgz + (blockIdx.x - 8) * 4 + (tid >> 6);
        uint4 z4 = {0, 0, 0, 0};
        ((uint4*)Zt)[(size_t)tile * 64 + (tid & 63)] = z4;
        ((uint4*)Yt)[(size_t)tile * 64 + (tid & 63)] = z4;
    }

    f16x8 bfr[4][2];
    #pragma unroll
    for (int nt = 0; nt < 4; ++nt)
        #pragma unroll
        for (int ks = 0; ks < 2; ++ks)
            bfr[nt][ks] = ld_frag(&C[(lr + 16 * nt) * 64 + ks * 32 + lg * 8]);

    #pragma unroll
    for (int g = 0; g < 2; ++g) {
        const int t0 = t0b + wv * 32 + g * 16;
        const int rowA = t0 + lr;
        const bool okA = rowA < T;
        f16x8 az[2], ay[2];
        #pragma unroll
        for (int ks = 0; ks < 2; ++ks) {
            if (okA) {
                az[ks] = ld_frag(&Z[(size_t)rowA * 64 + ks * 32 + lg * 8]);
                ay[ks] = ld_frag(&Y[(size_t)rowA * 64 + ks * 32 + lg * 8]);
            } else {
                az[ks] = (f16x8)(_Float16)0.f;
                ay[ks] = (f16x8)(_Float16)0.f;
            }
        }

        f32x4 accZ[4], accY[4];
        #pragma unroll
        for (int nt = 0; nt < 4; ++nt) { accZ[nt] = (f32x4){0,0,0,0}; accY[nt] = (f32x4){0,0,0,0}; }
        #pragma unroll
        for (int nt = 0; nt < 4; ++nt) {
            #pragma unroll
            for (int ks = 0; ks < 2; ++ks) {
                accZ[nt] = __builtin_amdgcn_mfma_f32_16x16x32_f16(az[ks], bfr[nt][ks], accZ[nt], 0, 0, 0);
                accY[nt] = __builtin_amdgcn_mfma_f32_16x16x32_f16(ay[ks], bfr[nt][ks], accY[nt], 0, 0, 0);
            }
        }

        // lane holds 4 consecutive t of channel sc -> one uint2 per tile
        #pragma unroll
        for (int nt = 0; nt < 4; ++nt) {
            const int sc = lr + 16 * nt;
            const int lt = wv * 32 + g * 16 + lg * 4;
            uint2 pz, py;
            pz.x = pkh2(accZ[nt][0], accZ[nt][1]);
            pz.y = pkh2(accZ[nt][2], accZ[nt][3]);
            py.x = pkh2(accY[nt][0], accY[nt][1]);
            py.y = pkh2(accY[nt][2], accY[nt][3]);
            *(uint2*)&ztl[sc * LSTR + lt] = pz;
            *(uint2*)&ytl[sc * LSTR + lt] = py;
        }
    }

    __syncthreads();

    // cooperative tiled stores: row (=s) fastest across lanes -> coalesced
    const int gbase = (GUARD >> 3) + blockIdx.x * 16;
    #pragma unroll
    for (int it = 0; it < 4; ++it) {
        const int chunk = it * 256 + tid;
        const int row = chunk & 63;           // s
        const int col = chunk >> 6;           // tile within block (0..15)
        const int tb  = t0b + col * 8;
        if (tb + 7 < T) {
            ((uint4*)Zt)[(size_t)(gbase + col) * 64 + row] =
                *(const uint4*)&ztl[row * LSTR + col * 8];
            ((uint4*)Yt)[(size_t)(gbase + col) * 64 + row] =
                *(const uint4*)&ytl[row * LSTR + col * 8];
        } else {
            #pragma unroll
            for (int h = 0; h < 8; ++h)
                if (tb + h < T) {
                    Zt[(size_t)(gbase + col) * 512 + row * 8 + h] = ztl[row * LSTR + col * 8 + h];
                    Yt[(size_t)(gbase + col) * 512 + row * 8 + h] = ytl[row * LSTR + col * 8 + h];
                }
        }
    }
}

// ---------------------------------------------------------------------------
// Kernel 2 (IIR, tiled coalesced feed): per basis b,
//   z[m] = 2r z[m-1] - r^2 z[m-2] + (c r) x[m-1-dl];  filtered[t]=sum_b z_b;
//   out = sigmoid(Yc + S + theta + filt)*W + Vo.
// Fast path (all dl==0): xi0 = t0-226 -> tile offset 6 is compile-time ->
// chunk words are the STATIC pick {cur.w, nxt.x, nxt.y, nxt.z}. Depth-8 tile
// ring; S(+theta) packed f16 mid-warmup; Yc = 6 coalesced dwordx4.
// ---------------------------------------------------------------------------
#define STEP3(u)                                                                 \
    _Pragma("unroll")                                                            \
    for (int b = 0; b < 3; ++b) {                                                \
        const float yn = fmaf(twr[b], y1[b], fmaf(mr2[b], y2[b], cr[b] * (u)));  \
        y2[b] = y1[b]; y1[b] = yn;                                               \
    }

#define PAIRW(wrd) {                                                             \
    union { uint u; _Float16 h[2]; } w_; w_.u = (wrd);                           \
    STEP3((float)w_.h[0]);                                                       \
    STEP3((float)w_.h[1]); }

#define CHUNK8F(cur, nxt) {                                                      \
    PAIRW((cur).w); PAIRW((nxt).x); PAIRW((nxt).y); PAIRW((nxt).z); }

__global__ __launch_bounds__(256, 3) void k_iir(
    const _Float16* __restrict__ Zt, const _Float16* __restrict__ Yt,
    const float* __restrict__ S,
    const float* __restrict__ K_spike, const float* __restrict__ tau_spike,
    const float* __restrict__ delta_spike, const float* __restrict__ theta,
    const float* __restrict__ W, const float* __restrict__ Vo,
    float* __restrict__ out, int T)
{
    const int tid = threadIdx.x;
    const int s   = tid & 63;
    const int wv  = tid >> 6;
    const int t0  = blockIdx.x * RB + wv * RW;
    if (t0 >= T) return;

    float twr[3], mr2[3], cr[3];
    #pragma unroll
    for (int b = 0; b < 3; ++b) {
        const float tau = __expf(tau_spike[b]);
        const float r   = __expf(-1.0f / tau);
        twr[b] = 2.0f * r;
        mr2[b] = -r * r;
        cr[b]  = K_spike[s * 3 + b] / tau * r;
    }
    int dl = (int)rintf(delta_spike[s]);
    dl = min(max(dl, 0), 30);
    const float th   = theta[s];
    const float wsub = W[s];
    const float vo   = Vo[0];

    float y1[3] = {0.f, 0.f, 0.f}, y2[3] = {0.f, 0.f, 0.f};

    if (__all(dl == 0)) {
        // ---- fast path: xb0 = t0-232 (tile-aligned), off = 6 (static)
        const int tile0 = (GUARD + t0 - 232) >> 3;
        const uint4* xb = (const uint4*)Zt + (size_t)tile0 * 64 + s;

        uint4 buf[8];
        #pragma unroll
        for (int p = 0; p < 8; ++p) buf[p] = xb[(size_t)p * 64];

        // ---- warmup chunks 0..23, prefetch tiles 8..31
        #pragma unroll 1
        for (int cc = 0; cc < 3; ++cc) {
            #pragma unroll
            for (int j = 0; j < 8; ++j) {
                const int c = cc * 8 + j;
                const uint4 cur = buf[j];
                const uint4 nxt = buf[(j + 1) & 7];
                buf[j] = xb[(size_t)(c + 8) * 64];
                __builtin_amdgcn_sched_barrier(0);
                CHUNK8F(cur, nxt);
            }
        }

        // ---- mid-warmup preloads: tail tiles, Yc, packed S+theta
        uint4 t32 = xb[(size_t)32 * 64];
        uint4 t33 = xb[(size_t)33 * 64];
        uint4 t34 = xb[(size_t)34 * 64];
        const uint4* yb = (const uint4*)Yt + (size_t)((GUARD + t0) >> 3) * 64 + s;
        uint4 yv[6];
        #pragma unroll
        for (int p = 0; p < 6; ++p) yv[p] = yb[(size_t)p * 64];
        uint spk[24];
        #pragma unroll
        for (int p = 0; p < 24; ++p) {
            const int t1 = min(t0 + 2 * p,     T - 1);
            const int t2 = min(t0 + 2 * p + 1, T - 1);
            spk[p] = pkh2(S[(size_t)t1 * 64 + s] + th, S[(size_t)t2 * 64 + s] + th);
        }

        // ---- warmup chunks 24..27 (tiles 24..31 live in buf[0..7])
        #pragma unroll
        for (int j = 0; j < 4; ++j) { CHUNK8F(buf[j], buf[j + 1]); }

        // ---- output chunks 28..33
        #pragma unroll
        for (int oc = 0; oc < 6; ++oc) {
            uint4 cur, nxt;
            if      (oc == 0) { cur = buf[4]; nxt = buf[5]; }
            else if (oc == 1) { cur = buf[5]; nxt = buf[6]; }
            else if (oc == 2) { cur = buf[6]; nxt = buf[7]; }
            else if (oc == 3) { cur = buf[7]; nxt = t32;    }
            else if (oc == 4) { cur = t32;    nxt = t33;    }
            else              { cur = t33;    nxt = t34;    }
            const uint sw[4] = { cur.w, nxt.x, nxt.y, nxt.z };
            union { uint4 v; _Float16 h[8]; } yw; yw.v = yv[oc];
            #pragma unroll
            for (int i = 0; i < 4; ++i) {
                union { uint u; _Float16 h[2]; } w; w.u = sw[i];
                #pragma unroll
                for (int hh = 0; hh < 2; ++hh) {
                    STEP3((float)w.h[hh]);
                    const int o = oc * 8 + i * 2 + hh;
                    const int t = t0 + o;
                    if (t < T) {
                        union { uint u; _Float16 h[2]; } sp; sp.u = spk[o >> 1];
                        const float xin = (float)yw.h[i * 2 + hh] + (float)sp.h[o & 1]
                                          + y1[0] + y1[1] + y1[2];
                        const float sig = 1.0f / (1.0f + __expf(-xin));
                        out[(size_t)t * 64 + s] = fmaf(sig, wsub, vo);
                    }
                }
            }
        }
    } else {
        // ---- generic per-lane-delay path (correct, slow; unused for bench data)
        const int xi0 = t0 - 226 - dl;
        for (int k = 0; k < 8 * NCH; ++k) {
            const int h = GUARD + xi0 + k;
            const float u = (float)Zt[(size_t)(h >> 3) * 512 + s * 8 + (h & 7)];
            STEP3(u);
            const int o = k - WU;
            if (o >= 0) {
                const int t = t0 + o;
                if (t < T) {
                    const int hy = GUARD + t;
                    const float yc = (float)Yt[(size_t)(hy >> 3) * 512 + s * 8 + (hy & 7)];
                    const float xin = yc + S[(size_t)t * 64 + s] + th
                                      + y1[0] + y1[1] + y1[2];
                    const float sig = 1.0f / (1.0f + __expf(-xin));
                    out[(size_t)t * 64 + s] = fmaf(sig, wsub, vo);
                }
            }
        }
    }
}

// ---------------------------------------------------------------------------
extern "C" void kernel_launch(void* const* d_in, const int* in_sizes, int n_in,
                              void* d_out, int out_size, void* d_ws, size_t ws_size,
                              hipStream_t stream)
{
    const float* S     = (const float*)d_in[0];
    const float* Y     = (const float*)d_in[1];
    const float* Z     = (const float*)d_in[2];
    const float* C     = (const float*)d_in[3];
    const float* Vo    = (const float*)d_in[4];
    const float* W     = (const float*)d_in[5];
    const float* theta = (const float*)d_in[6];
    const float* K     = (const float*)d_in[7];
    const float* tau   = (const float*)d_in[8];
    const float* delta = (const float*)d_in[9];
    const int T = in_sizes[0] / SUBS;

    const int rgz    = (GUARD + T + 7) >> 3;         // first fully-invalid tile
    const int ntiles = rgz + 44;
    _Float16* Zt = (_Float16*)d_ws;                  // ntiles*1024 B
    _Float16* Yt = (_Float16*)((char*)d_ws + (size_t)ntiles * 1024);

    k_mm<<<(T + 127) / 128, 256, 0, stream>>>(Z, Y, C, Zt, Yt, T, rgz);
    k_iir<<<(T + RB - 1) / RB, 256, 0, stream>>>(Zt, Yt, S, K, tau, delta, theta,
                                                 W, Vo, (float*)d_out, T);
}

// Round 14
// 49.257 us; speedup vs baseline: 2.6845x; 1.1431x over previous
//
#include <hip/hip_runtime.h>

#define SUBS  64
#define GUARD 256              // left guard halves per channel (32 tiles)
#define LB    32               // IIR block length (rows per wave)
#define JT    8                // history terms: 8*32 = 256 >= 200-tap support
#define LSTR  136              // k_mm LDS row stride (halves)

typedef _Float16 f16x8 __attribute__((ext_vector_type(8)));
typedef float    f32x4 __attribute__((ext_vector_type(4)));

__device__ inline f16x8 ld_frag(const float* p) {
    float4 a = *(const float4*)p;
    float4 b = *(const float4*)(p + 4);
    f16x8 f;
    f[0]=(_Float16)a.x; f[1]=(_Float16)a.y; f[2]=(_Float16)a.z; f[3]=(_Float16)a.w;
    f[4]=(_Float16)b.x; f[5]=(_Float16)b.y; f[6]=(_Float16)b.z; f[7]=(_Float16)b.w;
    return f;
}
__device__ inline uint pkh2(float a, float b) {
    union { _Float16 h[2]; uint u; } p;
    p.h[0] = (_Float16)a; p.h[1] = (_Float16)b; return p.u;
}

// ---------------------------------------------------------------------------
// Kernel 1 (f16 MFMA): tiled-transposed Zt/Yt ([tile][64 s][8 halves], tile=8
// consecutive t) + guard zeroing. Unchanged from R13 (measured ~10 us).
// ---------------------------------------------------------------------------
__global__ __launch_bounds__(256, 4) void k_mm(
    const float* __restrict__ Z, const float* __restrict__ Y,
    const float* __restrict__ C,
    _Float16* __restrict__ Zt, _Float16* __restrict__ Yt, int T, int rgz)
{
    __shared__ _Float16 ztl[SUBS * LSTR];
    __shared__ _Float16 ytl[SUBS * LSTR];
    const int tid  = threadIdx.x;
    const int lane = tid & 63;
    const int wv   = tid >> 6;
    const int lr   = lane & 15;
    const int lg   = lane >> 4;
    const int t0b  = blockIdx.x * 128;

    if (blockIdx.x < 8) {                     // left guard: tiles 0..31
        const int tile = blockIdx.x * 4 + (tid >> 6);
        uint4 z4 = {0, 0, 0, 0};
        ((uint4*)Zt)[(size_t)tile * 64 + (tid & 63)] = z4;
        ((uint4*)Yt)[(size_t)tile * 64 + (tid & 63)] = z4;
    } else if (blockIdx.x < 18) {             // right guard: tiles rgz..rgz+39
        const int tile = rgz + (blockIdx.x - 8) * 4 + (tid >> 6);
        uint4 z4 = {0, 0, 0, 0};
        ((uint4*)Zt)[(size_t)tile * 64 + (tid & 63)] = z4;
        ((uint4*)Yt)[(size_t)tile * 64 + (tid & 63)] = z4;
    }

    f16x8 bfr[4][2];
    #pragma unroll
    for (int nt = 0; nt < 4; ++nt)
        #pragma unroll
        for (int ks = 0; ks < 2; ++ks)
            bfr[nt][ks] = ld_frag(&C[(lr + 16 * nt) * 64 + ks * 32 + lg * 8]);

    #pragma unroll
    for (int g = 0; g < 2; ++g) {
        const int t0 = t0b + wv * 32 + g * 16;
        const int rowA = t0 + lr;
        const bool okA = rowA < T;
        f16x8 az[2], ay[2];
        #pragma unroll
        for (int ks = 0; ks < 2; ++ks) {
            if (okA) {
                az[ks] = ld_frag(&Z[(size_t)rowA * 64 + ks * 32 + lg * 8]);
                ay[ks] = ld_frag(&Y[(size_t)rowA * 64 + ks * 32 + lg * 8]);
            } else {
                az[ks] = (f16x8)(_Float16)0.f;
                ay[ks] = (f16x8)(_Float16)0.f;
            }
        }

        f32x4 accZ[4], accY[4];
        #pragma unroll
        for (int nt = 0; nt < 4; ++nt) { accZ[nt] = (f32x4){0,0,0,0}; accY[nt] = (f32x4){0,0,0,0}; }
        #pragma unroll
        for (int nt = 0; nt < 4; ++nt) {
            #pragma unroll
            for (int ks = 0; ks < 2; ++ks) {
                accZ[nt] = __builtin_amdgcn_mfma_f32_16x16x32_f16(az[ks], bfr[nt][ks], accZ[nt], 0, 0, 0);
                accY[nt] = __builtin_amdgcn_mfma_f32_16x16x32_f16(ay[ks], bfr[nt][ks], accY[nt], 0, 0, 0);
            }
        }

        #pragma unroll
        for (int nt = 0; nt < 4; ++nt) {
            const int sc = lr + 16 * nt;
            const int lt = wv * 32 + g * 16 + lg * 4;
            uint2 pz, py;
            pz.x = pkh2(accZ[nt][0], accZ[nt][1]);
            pz.y = pkh2(accZ[nt][2], accZ[nt][3]);
            py.x = pkh2(accY[nt][0], accY[nt][1]);
            py.y = pkh2(accY[nt][2], accY[nt][3]);
            *(uint2*)&ztl[sc * LSTR + lt] = pz;
            *(uint2*)&ytl[sc * LSTR + lt] = py;
        }
    }

    __syncthreads();

    const int gbase = (GUARD >> 3) + blockIdx.x * 16;
    #pragma unroll
    for (int it = 0; it < 4; ++it) {
        const int chunk = it * 256 + tid;
        const int row = chunk & 63;
        const int col = chunk >> 6;
        const int tb  = t0b + col * 8;
        if (tb + 7 < T) {
            ((uint4*)Zt)[(size_t)(gbase + col) * 64 + row] =
                *(const uint4*)&ztl[row * LSTR + col * 8];
            ((uint4*)Yt)[(size_t)(gbase + col) * 64 + row] =
                *(const uint4*)&ytl[row * LSTR + col * 8];
        } else {
            #pragma unroll
            for (int h = 0; h < 8; ++h)
                if (tb + h < T) {
                    Zt[(size_t)(gbase + col) * 512 + row * 8 + h] = ztl[row * LSTR + col * 8 + h];
                    Yt[(size_t)(gbase + col) * 512 + row * 8 + h] = ytl[row * LSTR + col * 8 + h];
                }
        }
    }
}

// ---------------------------------------------------------------------------
// IIR machinery. Per basis: z[m] = 2r z[m-1] - r^2 z[m-2] + cr*x[m-1].
// Block i (outputs t in [32i, 32i+32)) consumes x[32i-2 .. 32i+29] (32 steps);
// incoming state S_i = (z[32i-2], z[32i-3]).
// ---------------------------------------------------------------------------
#define STEP3(u)                                                                 \
    _Pragma("unroll")                                                            \
    for (int b = 0; b < 3; ++b) {                                                \
        const float yn = fmaf(twr[b], y1[b], fmaf(mr2[b], y2[b], cr[b] * (u)));  \
        y2[b] = y1[b]; y1[b] = yn;                                               \
    }

#define PAIRW(wrd) {                                                             \
    union { uint u; _Float16 h[2]; } w_; w_.u = (wrd);                           \
    STEP3((float)w_.h[0]);                                                       \
    STEP3((float)w_.h[1]); }

// ---------------------------------------------------------------------------
// Kernel 2 (k_state): per 32-row block, run 32 steps from rest, store the
// from-rest final state f_i = (y1,y2 per basis) -> fb[(i+8)*384 + c*64 + s].
// Waves with gi<0 zero the 8-entry guard.
// ---------------------------------------------------------------------------
__global__ __launch_bounds__(256, 4) void k_state(
    const _Float16* __restrict__ Zt,
    const float* __restrict__ K_spike, const float* __restrict__ tau_spike,
    float* __restrict__ fb, int NB)
{
    const int tid = threadIdx.x;
    const int s   = tid & 63;
    const int wv  = tid >> 6;
    const int gi  = blockIdx.x * 4 + wv - JT;     // -8 .. NB-1
    if (gi >= NB) return;
    float* fout = fb + (size_t)(gi + JT) * 384;
    if (gi < 0) {
        #pragma unroll
        for (int c = 0; c < 6; ++c) fout[c * 64 + s] = 0.f;
        return;
    }

    float twr[3], mr2[3], cr[3];
    #pragma unroll
    for (int b = 0; b < 3; ++b) {
        const float tau = __expf(tau_spike[b]);
        const float r   = __expf(-1.0f / tau);
        twr[b] = 2.0f * r;
        mr2[b] = -r * r;
        cr[b]  = K_spike[s * 3 + b] / tau * r;
    }

    // x tiles: halves GUARD+32*gi-2 .. +29 -> tiles (31+4*gi)..(+4)
    const uint4* xb = (const uint4*)Zt + (size_t)(31 + 4 * gi) * 64 + s;
    const uint4 x0 = xb[0];
    const uint4 x1 = xb[64];
    const uint4 x2 = xb[128];
    const uint4 x3 = xb[192];
    const uint4 x4 = xb[256];

    float y1[3] = {0.f, 0.f, 0.f}, y2[3] = {0.f, 0.f, 0.f};
    PAIRW(x0.w);
    PAIRW(x1.x); PAIRW(x1.y); PAIRW(x1.z); PAIRW(x1.w);
    PAIRW(x2.x); PAIRW(x2.y); PAIRW(x2.z); PAIRW(x2.w);
    PAIRW(x3.x); PAIRW(x3.y); PAIRW(x3.z); PAIRW(x3.w);
    PAIRW(x4.x); PAIRW(x4.y); PAIRW(x4.z);

    #pragma unroll
    for (int b = 0; b < 3; ++b) {
        fout[(2 * b)     * 64 + s] = y1[b];
        fout[(2 * b + 1) * 64 + s] = y2[b];
    }
}

// ---------------------------------------------------------------------------
// Kernel 3 (k_iir2): per block i, compose incoming state S_i from 8 previous
// from-rest states (Horner with closed-form M^32), then run 32 steps WITH
// outputs: out = sigmoid(Yc + S + theta + sum_b y1_b)*W + Vo.
// ---------------------------------------------------------------------------
__global__ __launch_bounds__(256, 3) void k_iir2(
    const _Float16* __restrict__ Zt, const _Float16* __restrict__ Yt,
    const float* __restrict__ S,
    const float* __restrict__ K_spike, const float* __restrict__ tau_spike,
    const float* __restrict__ delta_spike, const float* __restrict__ theta,
    const float* __restrict__ W, const float* __restrict__ Vo,
    const float* __restrict__ fb, float* __restrict__ out, int T, int NB)
{
    const int tid = threadIdx.x;
    const int s   = tid & 63;
    const int wv  = tid >> 6;
    const int i   = blockIdx.x * 4 + wv;
    if (i >= NB) return;
    const int t0 = i * LB;

    float twr[3], mr2[3], cr[3], taus[3];
    #pragma unroll
    for (int b = 0; b < 3; ++b) {
        const float tau = __expf(tau_spike[b]);
        taus[b] = tau;
        const float r = __expf(-1.0f / tau);
        twr[b] = 2.0f * r;
        mr2[b] = -r * r;
        cr[b]  = K_spike[s * 3 + b] / tau * r;
    }
    int dl = (int)rintf(delta_spike[s]);
    dl = min(max(dl, 0), 30);
    const float th   = theta[s];
    const float wsub = W[s];
    const float vo   = Vo[0];

    float y1[3], y2[3];

    if (__all(dl == 0)) {
        // ---- M^32 per basis: z[n+k] = (k+1) r^k z[n] - k r^(k+1) z[n-1]
        float aL[3], bL[3], cL[3], dL[3];
        #pragma unroll
        for (int b = 0; b < 3; ++b) {
            const float r   = 0.5f * twr[b];
            const float rm1 = __expf(-(float)(LB - 1) / taus[b]);  // r^31
            const float rl  = rm1 * r;                             // r^32
            const float rp  = rl * r;                              // r^33
            aL[b] = (float)(LB + 1) * rl;
            bL[b] = -(float)LB * rp;
            cL[b] = (float)LB * rm1;
            dL[b] = -(float)(LB - 1) * rl;
        }
        // ---- Horner over f_{i-8} .. f_{i-1}
        {
            const float* fq = fb + (size_t)i * 384;        // f(i-8)
            #pragma unroll
            for (int b = 0; b < 3; ++b) {
                y1[b] = fq[(2 * b) * 64 + s];
                y2[b] = fq[(2 * b + 1) * 64 + s];
            }
        }
        #pragma unroll
        for (int j = 7; j >= 1; --j) {
            const float* fq = fb + (size_t)(i + JT - j) * 384;
            #pragma unroll
            for (int b = 0; b < 3; ++b) {
                const float f1 = fq[(2 * b) * 64 + s];
                const float f2 = fq[(2 * b + 1) * 64 + s];
                const float n1 = fmaf(aL[b], y1[b], fmaf(bL[b], y2[b], f1));
                const float n2 = fmaf(cL[b], y1[b], fmaf(dL[b], y2[b], f2));
                y1[b] = n1; y2[b] = n2;
            }
        }

        // ---- loads: x tiles, Yt tiles, packed S+theta
        const uint4* xb = (const uint4*)Zt + (size_t)(31 + 4 * i) * 64 + s;
        const uint4 x0 = xb[0];
        const uint4 x1 = xb[64];
        const uint4 x2 = xb[128];
        const uint4 x3 = xb[192];
        const uint4 x4 = xb[256];
        const uint4* yb = (const uint4*)Yt + (size_t)(32 + 4 * i) * 64 + s;
        const uint4 yv0 = yb[0], yv1 = yb[64], yv2 = yb[128], yv3 = yb[192];

        uint spk[16];
        #pragma unroll
        for (int p = 0; p < 16; ++p) {
            const int t1 = min(t0 + 2 * p,     T - 1);
            const int t2 = min(t0 + 2 * p + 1, T - 1);
            spk[p] = pkh2(S[(size_t)t1 * 64 + s] + th, S[(size_t)t2 * 64 + s] + th);
        }

        uint xw[16] = { x0.w, x1.x, x1.y, x1.z, x1.w, x2.x, x2.y, x2.z,
                        x2.w, x3.x, x3.y, x3.z, x3.w, x4.x, x4.y, x4.z };
        uint yw[16] = { yv0.x, yv0.y, yv0.z, yv0.w, yv1.x, yv1.y, yv1.z, yv1.w,
                        yv2.x, yv2.y, yv2.z, yv2.w, yv3.x, yv3.y, yv3.z, yv3.w };

        #pragma unroll
        for (int w = 0; w < 16; ++w) {
            union { uint u; _Float16 h[2]; } wx; wx.u = xw[w];
            union { uint u; _Float16 h[2]; } wy; wy.u = yw[w];
            union { uint u; _Float16 h[2]; } wp; wp.u = spk[w];
            #pragma unroll
            for (int hh = 0; hh < 2; ++hh) {
                STEP3((float)wx.h[hh]);
                const int t = t0 + 2 * w + hh;
                if (t < T) {
                    const float xin = (float)wy.h[hh] + (float)wp.h[hh]
                                      + y1[0] + y1[1] + y1[2];
                    const float sig = 1.0f / (1.0f + __expf(-xin));
                    out[(size_t)t * 64 + s] = fmaf(sig, wsub, vo);
                }
            }
        }
    } else {
        // ---- generic per-lane-delay path (correct, slow; unused for bench)
        y1[0] = y1[1] = y1[2] = 0.f;
        y2[0] = y2[1] = y2[2] = 0.f;
        const int xi0 = t0 - 226 - dl;
        for (int k = 0; k < 224 + LB; ++k) {
            const int h = GUARD + xi0 + k;
            const float u = (float)Zt[(size_t)(h >> 3) * 512 + s * 8 + (h & 7)];
            STEP3(u);
            const int o = k - 224;
            if (o >= 0) {
                const int t = t0 + o;
                if (t < T) {
                    const int hy = GUARD + t;
                    const float yc = (float)Yt[(size_t)(hy >> 3) * 512 + s * 8 + (hy & 7)];
                    const float xin = yc + S[(size_t)t * 64 + s] + th
                                      + y1[0] + y1[1] + y1[2];
                    const float sig = 1.0f / (1.0f + __expf(-xin));
                    out[(size_t)t * 64 + s] = fmaf(sig, wsub, vo);
                }
            }
        }
    }
}

// ---------------------------------------------------------------------------
extern "C" void kernel_launch(void* const* d_in, const int* in_sizes, int n_in,
                              void* d_out, int out_size, void* d_ws, size_t ws_size,
                              hipStream_t stream)
{
    const float* S     = (const float*)d_in[0];
    const float* Y     = (const float*)d_in[1];
    const float* Z     = (const float*)d_in[2];
    const float* C     = (const float*)d_in[3];
    const float* Vo    = (const float*)d_in[4];
    const float* W     = (const float*)d_in[5];
    const float* theta = (const float*)d_in[6];
    const float* K     = (const float*)d_in[7];
    const float* tau   = (const float*)d_in[8];
    const float* delta = (const float*)d_in[9];
    const int T  = in_sizes[0] / SUBS;
    const int NB = (T + LB - 1) / LB;

    const int rgz    = (GUARD + T + 7) >> 3;
    const int ntiles = rgz + 44;
    _Float16* Zt = (_Float16*)d_ws;
    _Float16* Yt = (_Float16*)((char*)d_ws + (size_t)ntiles * 1024);
    float*    fb = (float*)((char*)d_ws + (size_t)ntiles * 2048);

    k_mm<<<(T + 127) / 128, 256, 0, stream>>>(Z, Y, C, Zt, Yt, T, rgz);
    k_state<<<(NB + JT + 3) / 4, 256, 0, stream>>>(Zt, K, tau, fb, NB);
    k_iir2<<<(NB + 3) / 4, 256, 0, stream>>>(Zt, Yt, S, K, tau, delta, theta,
                                             W, Vo, fb, (float*)d_out, T, NB);
}

// Round 15
// 46.549 us; speedup vs baseline: 2.8406x; 1.0582x over previous
//
#include <hip/hip_runtime.h>

#define SUBS  64
#define GUARD 256              // left guard halves per channel (32 tiles)
#define LB    32               // IIR block length (rows per run/wave)
#define JT    8                // history terms: 8*32 = 256 >= 200-tap support
#define LSTR  136              // k_mm LDS row stride (halves)

typedef _Float16 f16x8 __attribute__((ext_vector_type(8)));
typedef float    f32x4 __attribute__((ext_vector_type(4)));

__device__ inline f16x8 ld_frag(const float* p) {
    float4 a = *(const float4*)p;
    float4 b = *(const float4*)(p + 4);
    f16x8 f;
    f[0]=(_Float16)a.x; f[1]=(_Float16)a.y; f[2]=(_Float16)a.z; f[3]=(_Float16)a.w;
    f[4]=(_Float16)b.x; f[5]=(_Float16)b.y; f[6]=(_Float16)b.z; f[7]=(_Float16)b.w;
    return f;
}
__device__ inline uint pkh2(float a, float b) {
    union { _Float16 h[2]; uint u; } p;
    p.h[0] = (_Float16)a; p.h[1] = (_Float16)b; return p.u;
}

// IIR core: per basis, z[m] = 2r z[m-1] - r^2 z[m-2] + cr*x[m-1]
#define STEP3(u)                                                                 \
    _Pragma("unroll")                                                            \
    for (int b = 0; b < 3; ++b) {                                                \
        const float yn = fmaf(twr[b], y1[b], fmaf(mr2[b], y2[b], cr[b] * (u)));  \
        y2[b] = y1[b]; y1[b] = yn;                                               \
    }
#define PAIRW(wrd) {                                                             \
    union { uint u; _Float16 h[2]; } w_; w_.u = (wrd);                           \
    STEP3((float)w_.h[0]);                                                       \
    STEP3((float)w_.h[1]); }

// ---------------------------------------------------------------------------
// Kernel 1 (f16 MFMA + fused state runs): tiled-transposed Zt/Yt
// ([tile][64 s][8 halves], tile = 8 consecutive t), guard zeroing, and per
// wave a from-rest 32-step IIR run over its own LDS column -> fb state.
// Run g (aligned): consumes x[32g .. 32g+32), stores v-contribution
// f_g = (y1,y2 per basis) at fb[(g+JT)*384 + c*64 + s].
// ---------------------------------------------------------------------------
__global__ __launch_bounds__(256, 4) void k_mm(
    const float* __restrict__ Z, const float* __restrict__ Y,
    const float* __restrict__ C,
    const float* __restrict__ K_spike, const float* __restrict__ tau_spike,
    _Float16* __restrict__ Zt, _Float16* __restrict__ Yt,
    float* __restrict__ fb, int T, int rgz, int NB)
{
    __shared__ _Float16 ztl[SUBS * LSTR];
    __shared__ _Float16 ytl[SUBS * LSTR];
    const int tid  = threadIdx.x;
    const int lane = tid & 63;
    const int wv   = tid >> 6;
    const int lr   = lane & 15;
    const int lg   = lane >> 4;
    const int t0b  = blockIdx.x * 128;

    if (blockIdx.x < 8) {                     // left guard tiles 0..31
        const int tile = blockIdx.x * 4 + (tid >> 6);
        uint4 z4 = {0, 0, 0, 0};
        ((uint4*)Zt)[(size_t)tile * 64 + (tid & 63)] = z4;
        ((uint4*)Yt)[(size_t)tile * 64 + (tid & 63)] = z4;
    } else if (blockIdx.x < 18) {             // right guard tiles rgz..rgz+39
        const int tile = rgz + (blockIdx.x - 8) * 4 + (tid >> 6);
        uint4 z4 = {0, 0, 0, 0};
        ((uint4*)Zt)[(size_t)tile * 64 + (tid & 63)] = z4;
        ((uint4*)Yt)[(size_t)tile * 64 + (tid & 63)] = z4;
    }
    if (blockIdx.x == 0) {                    // fb guard slots (g = -8..-1)
        for (int idx = tid; idx < JT * 384; idx += 256) fb[idx] = 0.f;
    }

    f16x8 bfr[4][2];
    #pragma unroll
    for (int nt = 0; nt < 4; ++nt)
        #pragma unroll
        for (int ks = 0; ks < 2; ++ks)
            bfr[nt][ks] = ld_frag(&C[(lr + 16 * nt) * 64 + ks * 32 + lg * 8]);

    #pragma unroll
    for (int g = 0; g < 2; ++g) {
        const int t0 = t0b + wv * 32 + g * 16;
        const int rowA = t0 + lr;
        const bool okA = rowA < T;
        f16x8 az[2], ay[2];
        #pragma unroll
        for (int ks = 0; ks < 2; ++ks) {
            if (okA) {
                az[ks] = ld_frag(&Z[(size_t)rowA * 64 + ks * 32 + lg * 8]);
                ay[ks] = ld_frag(&Y[(size_t)rowA * 64 + ks * 32 + lg * 8]);
            } else {
                az[ks] = (f16x8)(_Float16)0.f;
                ay[ks] = (f16x8)(_Float16)0.f;
            }
        }

        f32x4 accZ[4], accY[4];
        #pragma unroll
        for (int nt = 0; nt < 4; ++nt) { accZ[nt] = (f32x4){0,0,0,0}; accY[nt] = (f32x4){0,0,0,0}; }
        #pragma unroll
        for (int nt = 0; nt < 4; ++nt) {
            #pragma unroll
            for (int ks = 0; ks < 2; ++ks) {
                accZ[nt] = __builtin_amdgcn_mfma_f32_16x16x32_f16(az[ks], bfr[nt][ks], accZ[nt], 0, 0, 0);
                accY[nt] = __builtin_amdgcn_mfma_f32_16x16x32_f16(ay[ks], bfr[nt][ks], accY[nt], 0, 0, 0);
            }
        }

        #pragma unroll
        for (int nt = 0; nt < 4; ++nt) {
            const int sc = lr + 16 * nt;
            const int lt = wv * 32 + g * 16 + lg * 4;
            uint2 pz, py;
            pz.x = pkh2(accZ[nt][0], accZ[nt][1]);
            pz.y = pkh2(accZ[nt][2], accZ[nt][3]);
            py.x = pkh2(accY[nt][0], accY[nt][1]);
            py.y = pkh2(accY[nt][2], accY[nt][3]);
            *(uint2*)&ztl[sc * LSTR + lt] = pz;
            *(uint2*)&ytl[sc * LSTR + lt] = py;
        }
    }

    __syncthreads();

    // cooperative tiled stores (row = s fastest -> coalesced)
    const int gbase = (GUARD >> 3) + blockIdx.x * 16;
    #pragma unroll
    for (int it = 0; it < 4; ++it) {
        const int chunk = it * 256 + tid;
        const int row = chunk & 63;
        const int col = chunk >> 6;
        const int tb  = t0b + col * 8;
        if (tb + 7 < T) {
            ((uint4*)Zt)[(size_t)(gbase + col) * 64 + row] =
                *(const uint4*)&ztl[row * LSTR + col * 8];
            ((uint4*)Yt)[(size_t)(gbase + col) * 64 + row] =
                *(const uint4*)&ytl[row * LSTR + col * 8];
        } else {
            #pragma unroll
            for (int h = 0; h < 8; ++h)
                if (tb + h < T) {
                    Zt[(size_t)(gbase + col) * 512 + row * 8 + h] = ztl[row * LSTR + col * 8 + h];
                    Yt[(size_t)(gbase + col) * 512 + row * 8 + h] = ytl[row * LSTR + col * 8 + h];
                }
        }
    }

    // ---- fused from-rest state run: wave wv handles run grun = blk*4 + wv
    const int grun = blockIdx.x * 4 + wv;
    if (grun < NB) {
        float twr[3], mr2[3], cr[3];
        #pragma unroll
        for (int b = 0; b < 3; ++b) {
            const float tau = __expf(tau_spike[b]);
            const float r   = __expf(-1.0f / tau);
            twr[b] = 2.0f * r;
            mr2[b] = -r * r;
            cr[b]  = K_spike[lane * 3 + b] / tau * r;
        }
        const uint* zr = (const uint*)ztl + lane * (LSTR / 2) + wv * 16;
        float y1[3] = {0.f, 0.f, 0.f}, y2[3] = {0.f, 0.f, 0.f};
        uint xa[8];
        #pragma unroll
        for (int k = 0; k < 8; ++k) xa[k] = zr[k];
        #pragma unroll
        for (int k = 0; k < 8; ++k) PAIRW(xa[k]);
        #pragma unroll
        for (int k = 0; k < 8; ++k) xa[k] = zr[8 + k];
        #pragma unroll
        for (int k = 0; k < 8; ++k) PAIRW(xa[k]);
        float* fout = fb + (size_t)(grun + JT) * 384;
        #pragma unroll
        for (int b = 0; b < 3; ++b) {
            fout[(2 * b)     * 64 + lane] = y1[b];
            fout[(2 * b + 1) * 64 + lane] = y2[b];
        }
    }
}

// ---------------------------------------------------------------------------
// Kernel 2 (k_iir2): compose v[32i] = sum_{j=1..8} M^{32(j-1)} f_{i-j}
// (Horner, closed-form M^32), emit outputs 32i, 32i+1 directly from v, then
// 30 steps over x[32i..32i+29] (4 aligned tiles) for the rest.
// out = sigmoid(Yc + S + theta + filtered)*W + Vo.
// ---------------------------------------------------------------------------
#define EMIT(o, f) {                                                             \
    const int t_ = t0 + (o);                                                     \
    if (t_ < T) {                                                                \
        union { uint u; _Float16 h[2]; } wy_; wy_.u = ywd[(o) >> 1];             \
        union { uint u; _Float16 h[2]; } wp_; wp_.u = spk[(o) >> 1];             \
        const float xin_ = (float)wy_.h[(o) & 1] + (float)wp_.h[(o) & 1] + (f);  \
        const float sig_ = 1.0f / (1.0f + __expf(-xin_));                        \
        out[(size_t)t_ * 64 + s] = fmaf(sig_, wsub, vo);                         \
    } }

__global__ __launch_bounds__(256, 3) void k_iir2(
    const _Float16* __restrict__ Zt, const _Float16* __restrict__ Yt,
    const float* __restrict__ S,
    const float* __restrict__ K_spike, const float* __restrict__ tau_spike,
    const float* __restrict__ delta_spike, const float* __restrict__ theta,
    const float* __restrict__ W, const float* __restrict__ Vo,
    const float* __restrict__ fb, float* __restrict__ out, int T, int NB)
{
    const int tid = threadIdx.x;
    const int s   = tid & 63;
    const int wv  = tid >> 6;
    const int i   = blockIdx.x * 4 + wv;
    if (i >= NB) return;
    const int t0 = i * LB;

    float twr[3], mr2[3], cr[3], taus[3];
    #pragma unroll
    for (int b = 0; b < 3; ++b) {
        const float tau = __expf(tau_spike[b]);
        taus[b] = tau;
        const float r = __expf(-1.0f / tau);
        twr[b] = 2.0f * r;
        mr2[b] = -r * r;
        cr[b]  = K_spike[s * 3 + b] / tau * r;
    }
    int dl = (int)rintf(delta_spike[s]);
    dl = min(max(dl, 0), 30);
    const float th   = theta[s];
    const float wsub = W[s];
    const float vo   = Vo[0];

    float y1[3], y2[3];

    if (__all(dl == 0)) {
        // M^32 per basis: z[n+k] = (k+1) r^k z[n] - k r^(k+1) z[n-1]
        float aL[3], bL[3], cL[3], dL[3];
        #pragma unroll
        for (int b = 0; b < 3; ++b) {
            const float r   = 0.5f * twr[b];
            const float rm1 = __expf(-(float)(LB - 1) / taus[b]);  // r^31
            const float rl  = rm1 * r;                             // r^32
            const float rp  = rl * r;                              // r^33
            aL[b] = (float)(LB + 1) * rl;
            bL[b] = -(float)LB * rp;
            cL[b] = (float)LB * rm1;
            dL[b] = -(float)(LB - 1) * rl;
        }
        // Horner over f_{i-8} .. f_{i-1} -> v[32i] = (z[32i], z[32i-1])
        {
            const float* fq = fb + (size_t)i * 384;       // f_{i-8}
            #pragma unroll
            for (int b = 0; b < 3; ++b) {
                y1[b] = fq[(2 * b) * 64 + s];
                y2[b] = fq[(2 * b + 1) * 64 + s];
            }
        }
        #pragma unroll
        for (int j = 7; j >= 1; --j) {
            const float* fq = fb + (size_t)(i + JT - j) * 384;
            #pragma unroll
            for (int b = 0; b < 3; ++b) {
                const float f1 = fq[(2 * b) * 64 + s];
                const float f2 = fq[(2 * b + 1) * 64 + s];
                const float n1 = fmaf(aL[b], y1[b], fmaf(bL[b], y2[b], f1));
                const float n2 = fmaf(cL[b], y1[b], fmaf(dL[b], y2[b], f2));
                y1[b] = n1; y2[b] = n2;
            }
        }

        // loads: 4 aligned x tiles, 4 Yc tiles, packed S+theta
        const uint4* xb = (const uint4*)Zt + (size_t)(32 + 4 * i) * 64 + s;
        const uint4 x0 = xb[0], x1 = xb[64], x2 = xb[128], x3 = xb[192];
        const uint4* yb = (const uint4*)Yt + (size_t)(32 + 4 * i) * 64 + s;
        const uint4 yv0 = yb[0], yv1 = yb[64], yv2 = yb[128], yv3 = yb[192];

        uint spk[16];
        #pragma unroll
        for (int p = 0; p < 16; ++p) {
            const int t1 = min(t0 + 2 * p,     T - 1);
            const int t2 = min(t0 + 2 * p + 1, T - 1);
            spk[p] = pkh2(S[(size_t)t1 * 64 + s] + th, S[(size_t)t2 * 64 + s] + th);
        }

        const uint xw[15] = { x0.x, x0.y, x0.z, x0.w, x1.x, x1.y, x1.z, x1.w,
                              x2.x, x2.y, x2.z, x2.w, x3.x, x3.y, x3.z };
        const uint ywd[16] = { yv0.x, yv0.y, yv0.z, yv0.w, yv1.x, yv1.y, yv1.z, yv1.w,
                               yv2.x, yv2.y, yv2.z, yv2.w, yv3.x, yv3.y, yv3.z, yv3.w };

        // outputs 0,1 directly from the composed state
        EMIT(0, y2[0] + y2[1] + y2[2]);
        EMIT(1, y1[0] + y1[1] + y1[2]);
        // 30 steps: word w covers outputs 2+2w, 3+2w
        #pragma unroll
        for (int w = 0; w < 15; ++w) {
            union { uint u; _Float16 h[2]; } wx; wx.u = xw[w];
            STEP3((float)wx.h[0]);
            EMIT(2 + 2 * w, y1[0] + y1[1] + y1[2]);
            STEP3((float)wx.h[1]);
            EMIT(3 + 2 * w, y1[0] + y1[1] + y1[2]);
        }
    } else {
        // generic per-lane-delay path (correct, slow; unused for bench data)
        y1[0] = y1[1] = y1[2] = 0.f;
        y2[0] = y2[1] = y2[2] = 0.f;
        const int xi0 = t0 - 226 - dl;
        for (int k = 0; k < 224 + LB; ++k) {
            const int h = GUARD + xi0 + k;
            const float u = (float)Zt[(size_t)(h >> 3) * 512 + s * 8 + (h & 7)];
            STEP3(u);
            const int o = k - 224;
            if (o >= 0) {
                const int t = t0 + o;
                if (t < T) {
                    const int hy = GUARD + t;
                    const float yc = (float)Yt[(size_t)(hy >> 3) * 512 + s * 8 + (hy & 7)];
                    const float xin = yc + S[(size_t)t * 64 + s] + th
                                      + y1[0] + y1[1] + y1[2];
                    const float sig = 1.0f / (1.0f + __expf(-xin));
                    out[(size_t)t * 64 + s] = fmaf(sig, wsub, vo);
                }
            }
        }
    }
}

// ---------------------------------------------------------------------------
extern "C" void kernel_launch(void* const* d_in, const int* in_sizes, int n_in,
                              void* d_out, int out_size, void* d_ws, size_t ws_size,
                              hipStream_t stream)
{
    const float* S     = (const float*)d_in[0];
    const float* Y     = (const float*)d_in[1];
    const float* Z     = (const float*)d_in[2];
    const float* C     = (const float*)d_in[3];
    const float* Vo    = (const float*)d_in[4];
    const float* W     = (const float*)d_in[5];
    const float* theta = (const float*)d_in[6];
    const float* K     = (const float*)d_in[7];
    const float* tau   = (const float*)d_in[8];
    const float* delta = (const float*)d_in[9];
    const int T  = in_sizes[0] / SUBS;
    const int NB = (T + LB - 1) / LB;

    const int rgz    = (GUARD + T + 7) >> 3;
    const int ntiles = rgz + 44;
    _Float16* Zt = (_Float16*)d_ws;
    _Float16* Yt = (_Float16*)((char*)d_ws + (size_t)ntiles * 1024);
    float*    fb = (float*)((char*)d_ws + (size_t)ntiles * 2048);

    k_mm<<<(T + 127) / 128, 256, 0, stream>>>(Z, Y, C, K, tau, Zt, Yt, fb, T, rgz, NB);
    k_iir2<<<(NB + 3) / 4, 256, 0, stream>>>(Zt, Yt, S, K, tau, delta, theta,
                                             W, Vo, fb, (float*)d_out, T, NB);
}